// Round 13
// baseline (7094.390 us; speedup 1.0000x reference)
//
#include <hip/hip_runtime.h>
#include <hip/hip_bf16.h>

#define TT 512
#define BB 256
#define II 13
#define HH 512
#define NBLK 64
#define NTH 256
#define NKT 17              // K tiles of 32 (K = 544 = 34 slices of 16)
#define RGS 8704            // shorts per region: 34 slices * 16 rows * 16 cols
#define XROW (BB * II)      // 3328

typedef __attribute__((ext_vector_type(8))) short short8;
typedef __attribute__((ext_vector_type(4))) float floatx4;
typedef __attribute__((ext_vector_type(4))) int intx4;

__device__ inline float sigm(float v) { return 1.f / (1.f + __expf(-v)); }
__device__ inline float tanh_(float v) {
    float e = __expf(-2.f * fabsf(v));
    float t = (1.f - e) / (1.f + e);
    return v < 0.f ? -t : t;
}
__device__ inline void split_bits(float v, unsigned short* hi, unsigned short* lo) {
    __hip_bfloat16 h = __float2bfloat16(v);
    float r = v - __bfloat162float(h);
    __hip_bfloat16 l = __float2bfloat16(r);
    *hi = __builtin_bit_cast(unsigned short, h);
    *lo = __builtin_bit_cast(unsigned short, l);
}

// ---- MALL-direct (uncached) path: sc0 sc1 bypasses vL1 AND L2. The ONLY
// protocol validated on this part (R5/R9/R10 passed; L2-local variant failed).
__device__ inline void arrive_mall(unsigned* p) {
    asm volatile("global_atomic_add %0, %1, off sc1" :: "v"(p), "v"(1u) : "memory");
}
__device__ inline unsigned poll_mall(const unsigned* p) {
    unsigned v;
    asm volatile("global_load_dword %0, %1, off sc0 sc1\n\ts_waitcnt vmcnt(0)"
                 : "=&v"(v) : "v"(p) : "memory");
    return v;
}
__device__ inline intx4 load_b128_uc(const void* p) {   // issue only; NO waitcnt
    intx4 v;
    asm volatile("global_load_dwordx4 %0, %1, off sc0 sc1" : "=v"(v) : "v"(p));
    return v;
}
__device__ inline void store_short_uc(void* p, unsigned short v) {
    unsigned vv = v;
    asm volatile("global_store_short %0, %1, off sc0 sc1" :: "v"(p), "v"(vv) : "memory");
}
__device__ inline void store_dword_uc(void* p, unsigned v) {
    asm volatile("global_store_dword %0, %1, off sc0 sc1" :: "v"(p), "v"(v) : "memory");
}
__device__ inline void store_f32_wt(float* p, float v) {
    asm volatile("global_store_dword %0, %1, off sc0 sc1" :: "v"(p), "v"(v) : "memory");
}

// region (buf, plane, chunk, wave, group) in shorts
#define REG(buf, plane, cc_, w, g) \
    ((((((buf) * 2 + (plane)) * 2 + (cc_)) * 4 + (w)) * 2 + (g)) * RGS)

// MFMA for one group: 17 kt x 4 gates x 3 hi/lo products, A-frags in regs
// (fully loaded + waitcnt'd BEFORE the call), W-frags from LDS (R10 layout).
__device__ __forceinline__ void mfma_group(
    const intx4 (&ah)[NKT], const intx4 (&al)[NKT], const unsigned short* Wfl,
    floatx4& gI, floatx4& gF, floatx4& gG, floatx4& gO)
{
    floatx4 aA[4], aB[4], aC[4];
#pragma unroll
    for (int g = 0; g < 4; ++g) {
        aA[g] = floatx4{0.f, 0.f, 0.f, 0.f};
        aB[g] = floatx4{0.f, 0.f, 0.f, 0.f};
        aC[g] = floatx4{0.f, 0.f, 0.f, 0.f};
    }
#pragma unroll
    for (int kt = 0; kt < NKT; ++kt) {
        short8 ch = __builtin_bit_cast(short8, ah[kt]);
        short8 cl = __builtin_bit_cast(short8, al[kt]);
#pragma unroll
        for (int g = 0; g < 4; ++g) {
            short8 wh = *(const short8*)(Wfl + ((g * 2 + 0) * NKT + kt) * 512);
            short8 wl = *(const short8*)(Wfl + ((g * 2 + 1) * NKT + kt) * 512);
            aA[g] = __builtin_amdgcn_mfma_f32_16x16x32_bf16(ch, wh, aA[g], 0, 0, 0);
            aB[g] = __builtin_amdgcn_mfma_f32_16x16x32_bf16(ch, wl, aB[g], 0, 0, 0);
            aC[g] = __builtin_amdgcn_mfma_f32_16x16x32_bf16(cl, wh, aC[g], 0, 0, 0);
        }
    }
    gI = aA[0] + aB[0] + aC[0];
    gF = aA[1] + aB[1] + aC[1];
    gG = aA[2] + aB[2] + aC[2];
    gO = aA[3] + aB[3] + aC[3];
}

// In-lane elementwise (all 4 gates of an element live in the same lane),
// h hi/lo store (MALL-direct), Y row-reduce + atomic.
__device__ __forceinline__ void finish_group(
    const floatx4& gI, const floatx4& gF, const floatx4& gG, const floatx4& gO,
    float (&cc)[4], unsigned short* stH, unsigned short* stL,
    float* __restrict__ Y, int yrow0, float woutv, int lane)
{
    const int col = lane & 15, rq = (lane >> 4) * 4;
#pragma unroll
    for (int r = 0; r < 4; ++r) {
        float ci = cc[r];
        ci = sigm(gF[r]) * ci + sigm(gI[r]) * tanh_(gG[r]);
        float h = sigm(gO[r]) * tanh_(ci);
        cc[r] = ci;
        unsigned short hi, lo;
        split_bits(h, &hi, &lo);
        store_short_uc(stH + (rq + r) * 16 + col, hi);
        store_short_uc(stL + (rq + r) * 16 + col, lo);
        float p = fmaxf(h, 0.f) * woutv;
        p += __shfl_xor(p, 1); p += __shfl_xor(p, 2);
        p += __shfl_xor(p, 4); p += __shfl_xor(p, 8);
        if (col == 0)
            atomicAdd(&Y[yrow0 + rq + r], p);
    }
}

__global__ void __launch_bounds__(NTH, 1)
lstm_persist(const float* __restrict__ X,   const float* __restrict__ Wih,
             const float* __restrict__ Whh, const float* __restrict__ bih,
             const float* __restrict__ bhh, const float* __restrict__ Wout,
             const float* __restrict__ bout, float* __restrict__ Y,
             unsigned short* __restrict__ hbuf, unsigned* __restrict__ bars)
{
    extern __shared__ char smem[];
    // W in MFMA-fragment order (R10-validated): frag(gate,plane,kt) = 1KB,
    // lane l owns bytes [16l,16l+16). Conflict-free ds_read_b128.
    unsigned short* Wf = (unsigned short*)smem;          // 4*2*17*512 shorts
    int* shint = (int*)(Wf + 4 * 2 * NKT * 512);

    const int tid = threadIdx.x;
    const int lane = tid & 63, wid = tid >> 6;

    // ---- role: rank 0..63 -> chunk c (128 batch rows), hidden slice hs ----
    if (tid == 0) {
        unsigned r = __hip_atomic_fetch_add(bars + 500, 1u,
                        __ATOMIC_RELAXED, __HIP_MEMORY_SCOPE_AGENT);
        shint[0] = (int)(r & 63u);
    }
    __syncthreads();
    const int rk = shint[0];
    const int c  = rk >> 5;
    const int hs = rk & 31;

    const int r15 = lane & 15;
    const int kgo = (lane >> 4) * 8;
    const int slb = kgo >> 4;
    const int laneoff = r15 * 16 + (kgo & 8);

    // ---- W slice -> Wf fragment layout ----
    for (int n = 0; n < 64; ++n) {
        int gate = n >> 4, hl = n & 15;
        int gr = gate * HH + hs * 16 + hl;   // gate rows in i,f,g,o order
        for (int k = tid; k < 544; k += NTH) {
            float v;
            if (k < HH)            v = Whh[gr * HH + k];
            else if (k < HH + II)  v = Wih[gr * II + (k - HH)];
            else if (k == HH + II) v = bih[gr] + bhh[gr];
            else                   v = 0.f;
            unsigned short hi, lo; split_bits(v, &hi, &lo);
            const int slot = (hl + 16 * ((k & 31) >> 3)) * 8 + (k & 7);
            Wf[((gate * 2 + 0) * NKT + (k >> 5)) * 512 + slot] = hi;
            Wf[((gate * 2 + 1) * NKT + (k >> 5)) * 512 + slot] = lo;
        }
    }
    // ---- hbuf init (MALL-direct). Every region written ONLY by its own
    // wave (c,wid) -> per-wave vmcnt(0) + arrive covers it. ----
    {
        unsigned* hw = (unsigned*)hbuf;
#pragma unroll
        for (int g = 0; g < 2; ++g)
#pragma unroll
            for (int img = 0; img < 4; ++img) {
                const int bd = (REG(img >> 1, img & 1, c, wid, g) + hs * 256) >> 1;
                store_dword_uc(hw + bd + lane, 0u);
                store_dword_uc(hw + bd + 64 + lane, 0u);
            }
        if (hs == 0) {   // slices 32,33 (x/bias/pad): zero all images
#pragma unroll
            for (int g = 0; g < 2; ++g)
#pragma unroll
                for (int img = 0; img < 4; ++img) {
                    const int bd = (REG(img >> 1, img & 1, c, wid, g) + 32 * 256) >> 1;
#pragma unroll
                    for (int j = 0; j < 4; ++j)
                        store_dword_uc(hw + bd + j * 64 + lane, 0u);
                }
            asm volatile("s_waitcnt vmcnt(0)" ::: "memory");
#pragma unroll
            for (int g = 0; g < 2; ++g) {
                if (lane < 16) {   // bias-one col 13, hi plane, both buffers
                    store_short_uc(hbuf + REG(0, 0, c, wid, g) + 32 * 256 + lane * 16 + 13, 0x3F80u);
                    store_short_uc(hbuf + REG(1, 0, c, wid, g) + 32 * 256 + lane * 16 + 13, 0x3F80u);
                }
                if (r15 < 13) {    // x_0 -> buf0
#pragma unroll
                    for (int rr = 0; rr < 4; ++rr) {
                        const int row = rr * 4 + (lane >> 4);
                        const int rg = c * 128 + wid * 32 + g * 16 + row;
                        unsigned short hi, lo;
                        split_bits(X[rg * II + r15], &hi, &lo);
                        store_short_uc(hbuf + REG(0, 0, c, wid, g) + 32 * 256 + row * 16 + r15, hi);
                        store_short_uc(hbuf + REG(0, 1, c, wid, g) + 32 * 256 + row * 16 + r15, lo);
                    }
                }
            }
        }
        // Y init — wave-aligned (fixes R12 race): wave (c,wid,hs) inits
        // exactly the Y elements its counter's atomics later touch:
        // t in [hs*16, hs*16+16), b in [c*128+wid*32, +32).
        const float b0 = bout[0];
        const int rb = c * 128 + wid * 32;
#pragma unroll
        for (int j = 0; j < 8; ++j) {
            const int e = j * 64 + lane;
            store_f32_wt(&Y[(hs * 16 + (e >> 5)) * BB + rb + (e & 31)], b0);
        }
    }
    __syncthreads();   // Wf ready for all waves
    asm volatile("s_waitcnt vmcnt(0)" ::: "memory");
    unsigned* cnt = bars + (c * 4 + wid) * 32;   // one counter per (c,wid)
    if (lane == 0) arrive_mall(cnt);             // init epoch

    const float woutv = Wout[hs * 16 + r15];
    float ccA[4] = {0.f, 0.f, 0.f, 0.f};
    float ccB[4] = {0.f, 0.f, 0.f, 0.f};
    const unsigned short* Wfl = Wf + lane * 8;
    const int rbase = c * 128 + wid * 32;   // group A rows; B = +16

    for (int t = 0; t < TT; ++t) {
        const int cur = t & 1, nxt = cur ^ 1;
        {   // whole-wave poll (uniform value -> uniform exit); bounded spin
            int guard = 0;
            const unsigned tgt = 32u * (unsigned)(t + 1);
            unsigned v;
            do { v = poll_mall(cnt); } while ((int)(v - tgt) < 0 && ++guard < (1 << 16));
        }

        const unsigned short* A0h = hbuf + REG(cur, 0, c, wid, 0) + laneoff;
        const unsigned short* A0l = hbuf + REG(cur, 1, c, wid, 0) + laneoff;
        const unsigned short* A1h = hbuf + REG(cur, 0, c, wid, 1) + laneoff;
        const unsigned short* A1l = hbuf + REG(cur, 1, c, wid, 1) + laneoff;

        // ---- group A: load 34 -> drain -> compute (R10-proven shape) ----
        intx4 ah[NKT], al[NKT];
#pragma unroll
        for (int kt = 0; kt < NKT; ++kt) {
            const int so = (kt * 2 + slb) * 256;
            ah[kt] = load_b128_uc(A0h + so);
            al[kt] = load_b128_uc(A0l + so);
        }
        asm volatile("s_waitcnt vmcnt(0)" ::: "memory");
        __builtin_amdgcn_sched_barrier(0);   // rule #18

        // x-stager (one hs per epoch): plain cached X loads, used later
        const bool stg = (t + 1 < TT) && (hs == ((t + 1) & 31));
        float xA0 = 0.f, xA1 = 0.f, xA2 = 0.f, xA3 = 0.f;
        float xB0 = 0.f, xB1 = 0.f, xB2 = 0.f, xB3 = 0.f;
        if (stg && r15 < 13) {
            const float* Xt = X + (t + 1) * XROW + r15;
            const int rgA = rbase + (lane >> 4);
            xA0 = Xt[(rgA     ) * II]; xA1 = Xt[(rgA +  4) * II];
            xA2 = Xt[(rgA +  8) * II]; xA3 = Xt[(rgA + 12) * II];
            xB0 = Xt[(rgA + 16) * II]; xB1 = Xt[(rgA + 20) * II];
            xB2 = Xt[(rgA + 24) * II]; xB3 = Xt[(rgA + 28) * II];
        }

        floatx4 gI, gF, gG, gO;
        mfma_group(ah, al, Wfl, gI, gF, gG, gO);
        __builtin_amdgcn_sched_barrier(0);   // A frags dead past here
        finish_group(gI, gF, gG, gO, ccA,
                     hbuf + REG(nxt, 0, c, wid, 0) + hs * 256,
                     hbuf + REG(nxt, 1, c, wid, 0) + hs * 256,
                     Y, t * BB + rbase, woutv, lane);
        if (stg && r15 < 13) {
            unsigned short hi, lo;
            const int row = lane >> 4;
            unsigned short* xb0 = hbuf + REG(nxt, 0, c, wid, 0) + 32 * 256 + r15;
            unsigned short* xb1 = hbuf + REG(nxt, 1, c, wid, 0) + 32 * 256 + r15;
            split_bits(xA0, &hi, &lo); store_short_uc(xb0 + (row     ) * 16, hi); store_short_uc(xb1 + (row     ) * 16, lo);
            split_bits(xA1, &hi, &lo); store_short_uc(xb0 + (row +  4) * 16, hi); store_short_uc(xb1 + (row +  4) * 16, lo);
            split_bits(xA2, &hi, &lo); store_short_uc(xb0 + (row +  8) * 16, hi); store_short_uc(xb1 + (row +  8) * 16, lo);
            split_bits(xA3, &hi, &lo); store_short_uc(xb0 + (row + 12) * 16, hi); store_short_uc(xb1 + (row + 12) * 16, lo);
        }

        // ---- group B: reuse the SAME frag arrays (registers recycled;
        // peak frag liveness stays ~136 VGPR — the R11/R12 spill fix) ----
#pragma unroll
        for (int kt = 0; kt < NKT; ++kt) {
            const int so = (kt * 2 + slb) * 256;
            ah[kt] = load_b128_uc(A1h + so);
            al[kt] = load_b128_uc(A1l + so);
        }
        asm volatile("s_waitcnt vmcnt(0)" ::: "memory");  // B ready + A stores drained
        __builtin_amdgcn_sched_barrier(0);

        mfma_group(ah, al, Wfl, gI, gF, gG, gO);
        __builtin_amdgcn_sched_barrier(0);
        finish_group(gI, gF, gG, gO, ccB,
                     hbuf + REG(nxt, 0, c, wid, 1) + hs * 256,
                     hbuf + REG(nxt, 1, c, wid, 1) + hs * 256,
                     Y, t * BB + rbase + 16, woutv, lane);
        if (stg && r15 < 13) {
            unsigned short hi, lo;
            const int row = lane >> 4;
            unsigned short* xb0 = hbuf + REG(nxt, 0, c, wid, 1) + 32 * 256 + r15;
            unsigned short* xb1 = hbuf + REG(nxt, 1, c, wid, 1) + 32 * 256 + r15;
            split_bits(xB0, &hi, &lo); store_short_uc(xb0 + (row     ) * 16, hi); store_short_uc(xb1 + (row     ) * 16, lo);
            split_bits(xB1, &hi, &lo); store_short_uc(xb0 + (row +  4) * 16, hi); store_short_uc(xb1 + (row +  4) * 16, lo);
            split_bits(xB2, &hi, &lo); store_short_uc(xb0 + (row +  8) * 16, hi); store_short_uc(xb1 + (row +  8) * 16, lo);
            split_bits(xB3, &hi, &lo); store_short_uc(xb0 + (row + 12) * 16, hi); store_short_uc(xb1 + (row + 12) * 16, lo);
        }
        asm volatile("s_waitcnt vmcnt(0)" ::: "memory");   // all h at MALL
        __builtin_amdgcn_sched_barrier(0);
        if (lane == 0) arrive_mall(cnt);
    }
}

extern "C" void kernel_launch(void* const* d_in, const int* in_sizes, int n_in,
                              void* d_out, int out_size, void* d_ws, size_t ws_size,
                              hipStream_t stream) {
    (void)in_sizes; (void)n_in; (void)out_size; (void)ws_size;
    const float* X    = (const float*)d_in[0];
    const float* Wih  = (const float*)d_in[1];
    const float* Whh  = (const float*)d_in[2];
    const float* bih  = (const float*)d_in[3];
    const float* bhh  = (const float*)d_in[4];
    const float* Wout = (const float*)d_in[5];
    const float* bout = (const float*)d_in[6];
    float* Y = (float*)d_out;

    // EXACT R5-R10 workspace footprint (1,116,160 B): bars [0,2048) +
    // hbuf at +2048 (R11/R12 grew this by 2KB — possible ws overflow).
    unsigned* bars = (unsigned*)d_ws;
    unsigned short* hbuf = (unsigned short*)((char*)d_ws + 2048);

    hipMemsetAsync(d_ws, 0, 2048, stream);

    const size_t lds = (size_t)(4 * 2 * NKT * 512 * 2) + 16;  // 139280
    hipFuncSetAttribute((const void*)lstm_persist,
                        hipFuncAttributeMaxDynamicSharedMemorySize, (int)lds);

    hipLaunchKernelGGL(lstm_persist, dim3(NBLK), dim3(NTH), lds, stream,
                       X, Wih, Whh, bih, bhh, Wout, bout, Y, hbuf, bars);
}

// Round 14
// 5591.957 us; speedup vs baseline: 1.2687x; 1.2687x over previous
//
#include <hip/hip_runtime.h>
#include <hip/hip_bf16.h>

#define TT 512
#define BB 256
#define II 13
#define HH 512
#define NBLK 256
#define NTH 256
#define NKT 17              // K tiles of 32 (K = 544 = 34 slices of 16)
#define NSL 34              // slices per plane
#define PS2 (NSL * 512)     // shorts per (buf,plane,bc) region: 17408
#define GST 18              // gbuf row stride (floats)
#define XROW (BB * II)      // 3328

typedef __attribute__((ext_vector_type(8))) short short8;
typedef __attribute__((ext_vector_type(4))) float floatx4;
typedef __attribute__((ext_vector_type(4))) int intx4;

__device__ inline float sigm(float v) { return 1.f / (1.f + __expf(-v)); }
__device__ inline float tanh_(float v) {
    float e = __expf(-2.f * fabsf(v));
    float t = (1.f - e) / (1.f + e);
    return v < 0.f ? -t : t;
}
__device__ inline void split_bits(float v, unsigned short* hi, unsigned short* lo) {
    __hip_bfloat16 h = __float2bfloat16(v);
    float r = v - __bfloat162float(h);
    __hip_bfloat16 l = __float2bfloat16(r);
    *hi = __builtin_bit_cast(unsigned short, h);
    *lo = __builtin_bit_cast(unsigned short, l);
}

// ---- MALL-direct (uncached) path: sc0 sc1 bypasses vL1 AND L2. The ONLY
// protocol validated on this part (R5/R9/R10/R13 passed; L2-local failed).
__device__ inline void arrive_mall(unsigned* p) {
    asm volatile("global_atomic_add %0, %1, off sc1" :: "v"(p), "v"(1u) : "memory");
}
// quad-counter poll: 4 per-wave counters share one 16B line -> one dwordx4
__device__ inline void poll4_mall(const unsigned* q, unsigned tgt) {
    int guard = 0;
    intx4 v;
    bool wait;
    do {
        asm volatile("global_load_dwordx4 %0, %1, off sc0 sc1\n\ts_waitcnt vmcnt(0)"
                     : "=&v"(v) : "v"(q) : "memory");
        wait = ((int)((unsigned)v[0] - tgt) < 0) | ((int)((unsigned)v[1] - tgt) < 0) |
               ((int)((unsigned)v[2] - tgt) < 0) | ((int)((unsigned)v[3] - tgt) < 0);
    } while (wait && ++guard < (1 << 16));
}
__device__ inline intx4 load_b128_uc(const void* p) {   // issue only; NO waitcnt
    intx4 v;
    asm volatile("global_load_dwordx4 %0, %1, off sc0 sc1" : "=v"(v) : "v"(p));
    return v;
}
__device__ inline float load_f32_uc_issue(const void* p) {   // issue only
    float v;
    asm volatile("global_load_dword %0, %1, off sc0 sc1" : "=v"(v) : "v"(p));
    return v;
}
__device__ inline void store_short_uc(void* p, unsigned short v) {
    unsigned vv = v;
    asm volatile("global_store_short %0, %1, off sc0 sc1" :: "v"(p), "v"(vv) : "memory");
}
__device__ inline void store_dword_uc(void* p, unsigned v) {
    asm volatile("global_store_dword %0, %1, off sc0 sc1" :: "v"(p), "v"(v) : "memory");
}
__device__ inline void store_f32_wt(float* p, float v) {
    asm volatile("global_store_dword %0, %1, off sc0 sc1" :: "v"(p), "v"(v) : "memory");
}

__global__ void __launch_bounds__(NTH, 1)
lstm_persist(const float* __restrict__ X,   const float* __restrict__ Wih,
             const float* __restrict__ Whh, const float* __restrict__ bih,
             const float* __restrict__ bhh, const float* __restrict__ Wout,
             const float* __restrict__ bout, float* __restrict__ Y,
             unsigned short* __restrict__ hbuf, float* __restrict__ P,
             unsigned* __restrict__ bars)
{
    extern __shared__ char smem[];
    // W in MFMA-fragment order (R10-validated): frag(gate,plane,kt) = 1KB,
    // lane l owns bytes [16l,16l+16). Conflict-free ds_read_b128.
    unsigned short* Wf = (unsigned short*)smem;          // 4*2*17*512 shorts
    float* gbuf = (float*)(Wf + 4 * 2 * NKT * 512);      // [128][GST] gates
    int* shint = (int*)(gbuf + 128 * GST);

    const int tid = threadIdx.x;
    const int lane = tid & 63, wid = tid >> 6;

    // ---- runtime role assignment: bc = physical XCD, hs = rank within XCD.
    if (tid == 0) {
        unsigned x = __builtin_amdgcn_s_getreg(20 | (3 << 11)) & 7u; // HW_REG_XCC_ID
        unsigned r = __hip_atomic_fetch_add(bars + 256 + x * 16, 1u,
                        __ATOMIC_RELAXED, __HIP_MEMORY_SCOPE_AGENT);
        shint[0] = (int)x;
        shint[1] = (int)(r & 31u);
    }
    __syncthreads();
    const int bc = shint[0];
    const int hs = shint[1];
    unsigned* bcnt4 = bars + bc * 32;   // 4 per-wave counters, one 16B line

    // Block-major hbuf layout (R9/R10): region(buf,plane) per bc; within
    // region [slice 0..33][row 0..31][col 0..15]; logical k = sl*16+col.
    const int regBase = bc * PS2;
#define REGION(buf, plane) (((buf) * 2 + (plane)) * 8 * PS2 + regBase)

    // ---- init: own-slice + (hs==0) shared x/bias slices. MALL-direct. ----
    {
        unsigned* hw = (unsigned*)hbuf;
        for (int bp = 0; bp < 4; ++bp)
            store_dword_uc(hw + (REGION(bp >> 1, bp & 1) >> 1) + hs * 256 + tid, 0u);
        if (hs == 0) {   // slices 32,33: x0/bias/padding, both bufs+planes
            for (int e = tid; e < 2 * 1024; e += NTH) {
                int buf = e >> 10, off = e & 1023;
                int row = (off >> 4) & 31, col = off & 15;
                unsigned short vh = 0, vl = 0;
                if (off < 512) {           // slice 32
                    if (col == 13) vh = 0x3F80u;                 // bias-one (hi)
                    else if (col < 13 && buf == 0)
                        split_bits(X[(bc * 32 + row) * II + col], &vh, &vl);
                }
                store_short_uc(hbuf + REGION(buf, 0) + 32 * 512 + off, vh);
                store_short_uc(hbuf + REGION(buf, 1) + 32 * 512 + off, vl);
            }
        }
        // NO Y init: the step-(t+1) reducer writes every Y element exactly once.
    }
    // ---- W slice -> LDS in fragment order (hi/lo split) ----
    for (int n = 0; n < 64; ++n) {
        int gate = n >> 4, hl = n & 15;
        int gr = gate * HH + hs * 16 + hl;   // global gate row (i,f,g,o order)
        for (int k = tid; k < 544; k += NTH) {
            float v;
            if (k < HH)            v = Whh[gr * HH + k];
            else if (k < HH + II)  v = Wih[gr * II + (k - HH)];
            else if (k == HH + II) v = bih[gr] + bhh[gr];
            else                   v = 0.f;
            unsigned short hi, lo; split_bits(v, &hi, &lo);
            const int slot = (hl + 16 * ((k & 31) >> 3)) * 8 + (k & 7);
            Wf[((gate * 2 + 0) * NKT + (k >> 5)) * 512 + slot] = hi;
            Wf[((gate * 2 + 1) * NKT + (k >> 5)) * 512 + slot] = lo;
        }
    }
    // ---- x_1 register preload (hs==1 stages x_1 at t=0) ----
    const int e0 = 2 * tid;
    const bool stv = (e0 < 32 * II);
    const int bl0 = e0 / II, xc0 = e0 - bl0 * II;
    const int e1 = e0 + 1;
    const int bl1 = e1 / II, xc1 = e1 - bl1 * II;
    float xr0 = 0.f, xr1 = 0.f;
    if (hs == 1 && stv) {
        const float2 v = *(const float2*)(X + XROW + bc * (32 * II) + e0);
        xr0 = v.x; xr1 = v.y;
    }

    __syncthreads();   // Wf ready; syncthreads drains every wave's init stores
    if (lane == 0) arrive_mall(bcnt4 + wid);   // per-wave init arrive (epoch 1)

    // ---- main recurrence (R10 compute structure; per-wave sync) ----
    const int mt = wid & 1;                 // batch 16-row half
    const int gp = wid >> 1;                // gate pair {2gp, 2gp+1}
    const int r15  = lane & 15;
    const int kgo  = (lane >> 4) * 8;
    const int slb  = kgo >> 4;              // extra slice within 32-wide tile
    const int lanehoff = (mt * 16 + r15) * 16 + (kgo & 8);
    const int lane8 = lane * 8;
    const unsigned short* F0 = Wf + ((4 * gp + 0) * NKT) * 512 + lane8; // g=2gp  hi
    const unsigned short* F1 = Wf + ((4 * gp + 1) * NKT) * 512 + lane8; // g=2gp  lo
    const unsigned short* F2 = Wf + ((4 * gp + 2) * NKT) * 512 + lane8; // g=2gp+1 hi
    const unsigned short* F3 = Wf + ((4 * gp + 3) * NKT) * 512 + lane8; // g=2gp+1 lo
    float c0 = 0.f, c1 = 0.f;
    const int ebl2 = tid >> 3;              // elementwise row (0..31)
    const int ej   = (tid & 7) * 2;         // elementwise col pair (ej, ej+1)
    const float2 wout2 = *(const float2*)&Wout[hs * 16 + ej];
    const float b0 = bout[0];

    for (int t = 0; t < TT; ++t) {
        const int cur = t & 1, nxt = cur ^ 1;
        poll4_mall(bcnt4, 32u * (unsigned)(t + 1));

        // Y-partial gather for step t-1 (wave 0): issued FIRST (oldest in
        // queue -> retired by the vmcnt(18) below). Zero extra RTs.
        float pred = 0.f;
        if (wid == 0 && t > 0) {
            const float* Pc = P + ((cur * 8 + bc) * 32 + (lane & 31)) * 32 + hs;
            pred = load_f32_uc_issue(Pc);
        }

        const unsigned short* Ahi = hbuf + REGION(cur, 0) + lanehoff;
        const unsigned short* Alo = hbuf + REGION(cur, 1) + lanehoff;

        intx4 ah[NKT], al[NKT];
#pragma unroll
        for (int kt = 0; kt < NKT; ++kt) {
            const int so = (kt * 2 + slb) * 512;
            ah[kt] = load_b128_uc(Ahi + so);
            al[kt] = load_b128_uc(Alo + so);
        }
        // W fragment prefetch (kt 0..3, 4-deep rotation) rides the MALL window
        short8 w0[4], w1[4], w2[4], w3[4];
#pragma unroll
        for (int j = 0; j < 4; ++j) {
            w0[j] = *(const short8*)(F0 + j * 512);
            w1[j] = *(const short8*)(F1 + j * 512);
            w2[j] = *(const short8*)(F2 + j * 512);
            w3[j] = *(const short8*)(F3 + j * 512);
        }
        floatx4 aA0 = {0,0,0,0}, aB0 = {0,0,0,0}, aC0 = {0,0,0,0};
        floatx4 aA1 = {0,0,0,0}, aB1 = {0,0,0,0}, aC1 = {0,0,0,0};

        // phase 1: kt 0..7 (first 16 A-loads; pred also retired by this wait)
        asm volatile("s_waitcnt vmcnt(18)" ::: "memory");
        __builtin_amdgcn_sched_barrier(0);   // rule #18
#pragma unroll
        for (int kt = 0; kt < 8; ++kt) {
            short8 bh0 = w0[kt & 3], bv0 = w1[kt & 3];
            short8 bh1 = w2[kt & 3], bv1 = w3[kt & 3];
            if (kt + 4 < NKT) {
                w0[kt & 3] = *(const short8*)(F0 + (kt + 4) * 512);
                w1[kt & 3] = *(const short8*)(F1 + (kt + 4) * 512);
                w2[kt & 3] = *(const short8*)(F2 + (kt + 4) * 512);
                w3[kt & 3] = *(const short8*)(F3 + (kt + 4) * 512);
            }
            short8 chi = __builtin_bit_cast(short8, ah[kt]);
            short8 clo = __builtin_bit_cast(short8, al[kt]);
            aA0 = __builtin_amdgcn_mfma_f32_16x16x32_bf16(chi, bh0, aA0, 0, 0, 0);
            aA1 = __builtin_amdgcn_mfma_f32_16x16x32_bf16(chi, bh1, aA1, 0, 0, 0);
            aB0 = __builtin_amdgcn_mfma_f32_16x16x32_bf16(chi, bv0, aB0, 0, 0, 0);
            aB1 = __builtin_amdgcn_mfma_f32_16x16x32_bf16(chi, bv1, aB1, 0, 0, 0);
            aC0 = __builtin_amdgcn_mfma_f32_16x16x32_bf16(clo, bh0, aC0, 0, 0, 0);
            aC1 = __builtin_amdgcn_mfma_f32_16x16x32_bf16(clo, bh1, aC1, 0, 0, 0);
        }
        // phase 2: remaining loads drained
        asm volatile("s_waitcnt vmcnt(0)" ::: "memory");
        __builtin_amdgcn_sched_barrier(0);
#pragma unroll
        for (int kt = 8; kt < NKT; ++kt) {
            short8 bh0 = w0[kt & 3], bv0 = w1[kt & 3];
            short8 bh1 = w2[kt & 3], bv1 = w3[kt & 3];
            if (kt + 4 < NKT) {
                w0[kt & 3] = *(const short8*)(F0 + (kt + 4) * 512);
                w1[kt & 3] = *(const short8*)(F1 + (kt + 4) * 512);
                w2[kt & 3] = *(const short8*)(F2 + (kt + 4) * 512);
                w3[kt & 3] = *(const short8*)(F3 + (kt + 4) * 512);
            }
            short8 chi = __builtin_bit_cast(short8, ah[kt]);
            short8 clo = __builtin_bit_cast(short8, al[kt]);
            aA0 = __builtin_amdgcn_mfma_f32_16x16x32_bf16(chi, bh0, aA0, 0, 0, 0);
            aA1 = __builtin_amdgcn_mfma_f32_16x16x32_bf16(chi, bh1, aA1, 0, 0, 0);
            aB0 = __builtin_amdgcn_mfma_f32_16x16x32_bf16(chi, bv0, aB0, 0, 0, 0);
            aB1 = __builtin_amdgcn_mfma_f32_16x16x32_bf16(chi, bv1, aB1, 0, 0, 0);
            aC0 = __builtin_amdgcn_mfma_f32_16x16x32_bf16(clo, bh0, aC0, 0, 0, 0);
            aC1 = __builtin_amdgcn_mfma_f32_16x16x32_bf16(clo, bh1, aC1, 0, 0, 0);
        }
        floatx4 acc0 = aA0 + aB0 + aC0;
        floatx4 acc1 = aA1 + aB1 + aC1;

        {   // stage gates to LDS  (D frag: row=(lane>>4)*4+r, col=lane&15)
            const int b0r = mt * 16 + (lane >> 4) * 4;
            const int g0 = gp * 2;
#pragma unroll
            for (int r = 0; r < 4; ++r) {
                gbuf[((g0    ) * 32 + b0r + r) * GST + r15] = acc0[r];
                gbuf[((g0 + 1) * 32 + b0r + r) * GST + r15] = acc1[r];
            }
        }
        __syncthreads();   // the only intra-step block barrier (gbuf ready)

        // Y[t-1] reduction (wave 0): pred long since retired; off hot path
        if (wid == 0 && t > 0) {
            float v = pred;
            v += __shfl_xor(v, 1);  v += __shfl_xor(v, 2);
            v += __shfl_xor(v, 4);  v += __shfl_xor(v, 8);
            v += __shfl_xor(v, 16);
            if (lane == 0)
                store_f32_wt(&Y[(t - 1) * BB + bc * 32 + hs], v + b0);
        }
        {   // elementwise: thread owns (row=ebl2, cols ej, ej+1)
            const float2 gi = *(const float2*)&gbuf[(0 * 32 + ebl2) * GST + ej];
            const float2 gf = *(const float2*)&gbuf[(1 * 32 + ebl2) * GST + ej];
            const float2 gg = *(const float2*)&gbuf[(2 * 32 + ebl2) * GST + ej];
            const float2 go = *(const float2*)&gbuf[(3 * 32 + ebl2) * GST + ej];

            c0 = sigm(gf.x) * c0 + sigm(gi.x) * tanh_(gg.x);
            float ha = sigm(go.x) * tanh_(c0);
            c1 = sigm(gf.y) * c1 + sigm(gi.y) * tanh_(gg.y);
            float hb = sigm(go.y) * tanh_(c1);

            // coalesced h write: one dword per plane into own slice hs
            unsigned short ha_hi, ha_lo, hb_hi, hb_lo;
            split_bits(ha, &ha_hi, &ha_lo);
            split_bits(hb, &hb_hi, &hb_lo);
            unsigned* hw = (unsigned*)hbuf;
            const int woff = hs * 256 + ebl2 * 8 + (tid & 7);
            store_dword_uc(hw + (REGION(nxt, 0) >> 1) + woff,
                           (unsigned)ha_hi | ((unsigned)hb_hi << 16));
            store_dword_uc(hw + (REGION(nxt, 1) >> 1) + woff,
                           (unsigned)ha_lo | ((unsigned)hb_lo << 16));

            // Y partial: uncontended f32 store (replaces 32-way MALL atomics)
            float p = fmaxf(ha, 0.f) * wout2.x + fmaxf(hb, 0.f) * wout2.y;
#pragma unroll
            for (int s = 4; s >= 1; s >>= 1)
                p += __shfl_xor(p, s);
            if ((tid & 7) == 0)
                store_dword_uc(P + ((nxt * 8 + bc) * 32 + hs) * 32 + ebl2,
                               __builtin_bit_cast(unsigned, p));
        }
        // rotating x-stager: owner of time s stages at t=s-1 from regs
        if (t + 1 < TT && hs == ((t + 1) & 31) && stv) {
            unsigned short hi, lo;
            split_bits(xr0, &hi, &lo);
            store_short_uc(hbuf + REGION(nxt, 0) + 32 * 512 + bl0 * 16 + xc0, hi);
            store_short_uc(hbuf + REGION(nxt, 1) + 32 * 512 + bl0 * 16 + xc0, lo);
            split_bits(xr1, &hi, &lo);
            store_short_uc(hbuf + REGION(nxt, 0) + 32 * 512 + bl1 * 16 + xc1, hi);
            store_short_uc(hbuf + REGION(nxt, 1) + 32 * 512 + bl1 * 16 + xc1, lo);
        }
        if (t + 2 < TT && hs == ((t + 2) & 31) && stv) {
            const float2 v = *(const float2*)(X + (t + 2) * XROW + bc * (32 * II) + e0);
            xr0 = v.x; xr1 = v.y;
        }
        // per-wave drain + arrive (no block-wide coupling)
        asm volatile("s_waitcnt vmcnt(0)" ::: "memory");
        __builtin_amdgcn_sched_barrier(0);
        if (lane == 0) arrive_mall(bcnt4 + wid);
    }

    // ---- epilogue: reduce Y[TT-1] (partials written at t=TT-1, parity 0) ----
    poll4_mall(bcnt4, 32u * (unsigned)(TT + 1));
    if (wid == 0) {
        const float* Pc = P + (((TT & 1) * 8 + bc) * 32 + (lane & 31)) * 32 + hs;
        float v = load_f32_uc_issue(Pc);
        asm volatile("s_waitcnt vmcnt(0)" ::: "memory");
        __builtin_amdgcn_sched_barrier(0);
        v += __shfl_xor(v, 1);  v += __shfl_xor(v, 2);
        v += __shfl_xor(v, 4);  v += __shfl_xor(v, 8);
        v += __shfl_xor(v, 16);
        if (lane == 0)
            store_f32_wt(&Y[(TT - 1) * BB + bc * 32 + hs], v + b0);
    }
}

extern "C" void kernel_launch(void* const* d_in, const int* in_sizes, int n_in,
                              void* d_out, int out_size, void* d_ws, size_t ws_size,
                              hipStream_t stream) {
    (void)in_sizes; (void)n_in; (void)out_size; (void)ws_size;
    const float* X    = (const float*)d_in[0];
    const float* Wih  = (const float*)d_in[1];
    const float* Whh  = (const float*)d_in[2];
    const float* bih  = (const float*)d_in[3];
    const float* bhh  = (const float*)d_in[4];
    const float* Wout = (const float*)d_in[5];
    const float* bout = (const float*)d_in[6];
    float* Y = (float*)d_out;

    unsigned* bars = (unsigned*)d_ws;                                  // [0, 2048)
    unsigned short* hbuf = (unsigned short*)((char*)d_ws + 2048);      // 1,114,112 B
    float* P = (float*)((char*)d_ws + 2048 + 32 * PS2 * 2);            // 65,536 B

    hipMemsetAsync(d_ws, 0, 2048, stream);

    const size_t lds = (size_t)(4 * 2 * NKT * 512 * 2) + 128 * GST * 4 + 16;  // 148496
    hipFuncSetAttribute((const void*)lstm_persist,
                        hipFuncAttributeMaxDynamicSharedMemorySize, (int)lds);

    hipLaunchKernelGGL(lstm_persist, dim3(NBLK), dim3(NTH), lds, stream,
                       X, Wih, Whh, bih, bhh, Wout, bout, Y, hbuf, P, bars);
}

// Round 15
// 2377.056 us; speedup vs baseline: 2.9845x; 2.3525x over previous
//
#include <hip/hip_runtime.h>
#include <hip/hip_bf16.h>

#define TT 512
#define BB 256
#define II 13
#define HH 512
#define NBLK 256
#define NTH 256
#define NKT 17              // K tiles of 32 (K = 544 = 34 slices of 16)
#define NSL 34              // slices per plane
#define PS2 (NSL * 512)     // shorts per (buf,plane,bc) region: 17408
#define GST 18              // gbuf row stride (floats)
#define XROW (BB * II)      // 3328

typedef __attribute__((ext_vector_type(8))) short short8;
typedef __attribute__((ext_vector_type(4))) float floatx4;
typedef __attribute__((ext_vector_type(4))) int intx4;

__device__ inline float sigm(float v) { return 1.f / (1.f + __expf(-v)); }
__device__ inline float tanh_(float v) {
    float e = __expf(-2.f * fabsf(v));
    float t = (1.f - e) / (1.f + e);
    return v < 0.f ? -t : t;
}
__device__ inline void split_bits(float v, unsigned short* hi, unsigned short* lo) {
    __hip_bfloat16 h = __float2bfloat16(v);
    float r = v - __bfloat162float(h);
    __hip_bfloat16 l = __float2bfloat16(r);
    *hi = __builtin_bit_cast(unsigned short, h);
    *lo = __builtin_bit_cast(unsigned short, l);
}

// ---- MALL-direct (uncached) path: sc0 sc1 bypasses vL1 AND L2. The ONLY
// protocol validated on this part (R5/R9/R10 passed; L2-local variant failed).
__device__ inline unsigned poll_mall(const unsigned* p) {
    unsigned v;
    asm volatile("global_load_dword %0, %1, off sc0 sc1\n\ts_waitcnt vmcnt(0)"
                 : "=&v"(v) : "v"(p) : "memory");
    return v;
}
__device__ inline void arrive_mall(unsigned* p) {
    asm volatile("global_atomic_add %0, %1, off sc1" :: "v"(p), "v"(1u) : "memory");
}
__device__ inline intx4 load_b128_uc(const void* p) {   // issue only; NO waitcnt
    intx4 v;
    asm volatile("global_load_dwordx4 %0, %1, off sc0 sc1" : "=v"(v) : "v"(p));
    return v;
}
__device__ inline float load_f32_uc_issue(const void* p) {   // issue only
    float v;
    asm volatile("global_load_dword %0, %1, off sc0 sc1" : "=v"(v) : "v"(p));
    return v;
}
__device__ inline void store_short_uc(void* p, unsigned short v) {
    unsigned vv = v;
    asm volatile("global_store_short %0, %1, off sc0 sc1" :: "v"(p), "v"(vv) : "memory");
}
__device__ inline void store_dword_uc(void* p, unsigned v) {
    asm volatile("global_store_dword %0, %1, off sc0 sc1" :: "v"(p), "v"(v) : "memory");
}
__device__ inline void store_f32_wt(float* p, float v) {
    asm volatile("global_store_dword %0, %1, off sc0 sc1" :: "v"(p), "v"(v) : "memory");
}

// In-XCD barrier, counter at MALL (R10-proven): __syncthreads drains each
// wave's vmcnt -> all sc0sc1 stores are AT the MALL before tid0's arrive.
// tid0-only poll. Bounded spin.
__device__ inline void barrier_xcd(unsigned* cnt, unsigned target) {
    __syncthreads();
    if (threadIdx.x == 0) {
        arrive_mall(cnt);
        int guard = 0;
        unsigned v;
        do { v = poll_mall(cnt); } while ((int)(v - target) < 0 && ++guard < (1 << 16));
    }
    __syncthreads();
}

__global__ void __launch_bounds__(NTH, 1)
lstm_persist(const float* __restrict__ X,   const float* __restrict__ Wih,
             const float* __restrict__ Whh, const float* __restrict__ bih,
             const float* __restrict__ bhh, const float* __restrict__ Wout,
             const float* __restrict__ bout, float* __restrict__ Y,
             unsigned short* __restrict__ hbuf, float* __restrict__ P,
             unsigned* __restrict__ bars)
{
    extern __shared__ char smem[];
    // W in MFMA-fragment order (R10-validated): frag(gate,plane,kt) = 1KB,
    // lane l owns bytes [16l,16l+16). Conflict-free ds_read_b128.
    unsigned short* Wf = (unsigned short*)smem;          // 4*2*17*512 shorts
    float* gbuf = (float*)(Wf + 4 * 2 * NKT * 512);      // [128][GST] gates
    int* shint = (int*)(gbuf + 128 * GST);

    const int tid = threadIdx.x;

    // ---- runtime role assignment: bc = physical XCD, hs = rank within XCD.
    if (tid == 0) {
        unsigned x = __builtin_amdgcn_s_getreg(20 | (3 << 11)) & 7u; // HW_REG_XCC_ID
        unsigned r = __hip_atomic_fetch_add(bars + 256 + x * 16, 1u,
                        __ATOMIC_RELAXED, __HIP_MEMORY_SCOPE_AGENT);
        shint[0] = (int)x;
        shint[1] = (int)(r & 31u);
    }
    __syncthreads();
    const int bc = shint[0];
    const int hs = shint[1];
    unsigned* bcnt = bars + bc * 32;

    // Block-major hbuf layout (R9/R10): region(buf,plane) per bc; within
    // region [slice 0..33][row 0..31][col 0..15]; logical k = sl*16+col.
    const int regBase = bc * PS2;
#define REGION(buf, plane) (((buf) * 2 + (plane)) * 8 * PS2 + regBase)

    // ---- init: own-slice + (hs==0) shared x/bias slices. MALL-direct.
    // NO Y init: the deferred reducer writes every Y element exactly once. ----
    {
        unsigned* hw = (unsigned*)hbuf;
        for (int bp = 0; bp < 4; ++bp)
            store_dword_uc(hw + (REGION(bp >> 1, bp & 1) >> 1) + hs * 256 + tid, 0u);
        if (hs == 0) {   // slices 32,33: x0/bias/padding, both bufs+planes
            for (int e = tid; e < 2 * 1024; e += NTH) {
                int buf = e >> 10, off = e & 1023;
                int row = (off >> 4) & 31, col = off & 15;
                unsigned short vh = 0, vl = 0;
                if (off < 512) {           // slice 32
                    if (col == 13) vh = 0x3F80u;                 // bias-one (hi)
                    else if (col < 13 && buf == 0)
                        split_bits(X[(bc * 32 + row) * II + col], &vh, &vl);
                }
                store_short_uc(hbuf + REGION(buf, 0) + 32 * 512 + off, vh);
                store_short_uc(hbuf + REGION(buf, 1) + 32 * 512 + off, vl);
            }
        }
    }
    // ---- W slice -> LDS in fragment order (hi/lo split) ----
    for (int n = 0; n < 64; ++n) {
        int gate = n >> 4, hl = n & 15;
        int gr = gate * HH + hs * 16 + hl;   // global gate row (i,f,g,o order)
        for (int k = tid; k < 544; k += NTH) {
            float v;
            if (k < HH)            v = Whh[gr * HH + k];
            else if (k < HH + II)  v = Wih[gr * II + (k - HH)];
            else if (k == HH + II) v = bih[gr] + bhh[gr];
            else                   v = 0.f;
            unsigned short hi, lo; split_bits(v, &hi, &lo);
            const int slot = (hl + 16 * ((k & 31) >> 3)) * 8 + (k & 7);
            Wf[((gate * 2 + 0) * NKT + (k >> 5)) * 512 + slot] = hi;
            Wf[((gate * 2 + 1) * NKT + (k >> 5)) * 512 + slot] = lo;
        }
    }
    // ---- x_1 register preload (hs==1 stages x_1 at t=0) ----
    const int e0 = 2 * tid;
    const bool stv = (e0 < 32 * II);
    const int bl0 = e0 / II, xc0 = e0 - bl0 * II;
    const int e1 = e0 + 1;
    const int bl1 = e1 / II, xc1 = e1 - bl1 * II;
    float xr0 = 0.f, xr1 = 0.f;
    if (hs == 1 && stv) {
        const float2 v = *(const float2*)(X + XROW + bc * (32 * II) + e0);
        xr0 = v.x; xr1 = v.y;
    }

    barrier_xcd(bcnt, 32u);   // init done (epoch 1)

    // ---- main recurrence (R10 structure; only Y-path changed) ----
    const int lane = tid & 63, wid = tid >> 6;
    const int mt = wid & 1;                 // batch 16-row half
    const int gp = wid >> 1;                // gate pair {2gp, 2gp+1}
    const int r15  = lane & 15;
    const int kgo  = (lane >> 4) * 8;
    const int slb  = kgo >> 4;              // extra slice within 32-wide tile
    const int lanehoff = (mt * 16 + r15) * 16 + (kgo & 8);
    const int lane8 = lane * 8;
    const unsigned short* F0 = Wf + ((4 * gp + 0) * NKT) * 512 + lane8; // g=2gp  hi
    const unsigned short* F1 = Wf + ((4 * gp + 1) * NKT) * 512 + lane8; // g=2gp  lo
    const unsigned short* F2 = Wf + ((4 * gp + 2) * NKT) * 512 + lane8; // g=2gp+1 hi
    const unsigned short* F3 = Wf + ((4 * gp + 3) * NKT) * 512 + lane8; // g=2gp+1 lo
    float c0 = 0.f, c1 = 0.f;
    const int ebl2 = tid >> 3;              // elementwise row (0..31)
    const int ej   = (tid & 7) * 2;         // elementwise col pair (ej, ej+1)
    const float2 wout2 = *(const float2*)&Wout[hs * 16 + ej];
    const float b0 = bout[0];

    for (int t = 0; t < TT; ++t) {
        const int cur = t & 1, nxt = cur ^ 1;

        // Y-partial gather for step t-1 (wave 0): issued FIRST (oldest in
        // queue -> retired by the vmcnt(18) below). Zero extra RTs.
        float pred = 0.f;
        if (wid == 0 && t > 0) {
            const float* Pc = P + ((cur * 8 + bc) * 32 + (lane & 31)) * 32 + hs;
            pred = load_f32_uc_issue(Pc);
        }

        const unsigned short* Ahi = hbuf + REGION(cur, 0) + lanehoff;
        const unsigned short* Alo = hbuf + REGION(cur, 1) + lanehoff;

        // issue all 34 A-tile loads (MALL-direct, coalesced)
        intx4 ah[NKT], al[NKT];
#pragma unroll
        for (int kt = 0; kt < NKT; ++kt) {
            const int so = (kt * 2 + slb) * 512;
            ah[kt] = load_b128_uc(Ahi + so);
            al[kt] = load_b128_uc(Alo + so);
        }
        // W fragment prefetch (kt 0..3, 4-deep rotation) rides the MALL window
        short8 w0[4], w1[4], w2[4], w3[4];
#pragma unroll
        for (int j = 0; j < 4; ++j) {
            w0[j] = *(const short8*)(F0 + j * 512);
            w1[j] = *(const short8*)(F1 + j * 512);
            w2[j] = *(const short8*)(F2 + j * 512);
            w3[j] = *(const short8*)(F3 + j * 512);
        }
        floatx4 aA0 = {0,0,0,0}, aB0 = {0,0,0,0}, aC0 = {0,0,0,0};
        floatx4 aA1 = {0,0,0,0}, aB1 = {0,0,0,0}, aC1 = {0,0,0,0};

        // phase 1: kt 0..7 (pred + first 16 A-loads retired at vmcnt 18)
        asm volatile("s_waitcnt vmcnt(18)" ::: "memory");
        __builtin_amdgcn_sched_barrier(0);   // rule #18
#pragma unroll
        for (int kt = 0; kt < 8; ++kt) {
            short8 bh0 = w0[kt & 3], bv0 = w1[kt & 3];
            short8 bh1 = w2[kt & 3], bv1 = w3[kt & 3];
            if (kt + 4 < NKT) {
                w0[kt & 3] = *(const short8*)(F0 + (kt + 4) * 512);
                w1[kt & 3] = *(const short8*)(F1 + (kt + 4) * 512);
                w2[kt & 3] = *(const short8*)(F2 + (kt + 4) * 512);
                w3[kt & 3] = *(const short8*)(F3 + (kt + 4) * 512);
            }
            short8 chi = __builtin_bit_cast(short8, ah[kt]);
            short8 clo = __builtin_bit_cast(short8, al[kt]);
            aA0 = __builtin_amdgcn_mfma_f32_16x16x32_bf16(chi, bh0, aA0, 0, 0, 0);
            aA1 = __builtin_amdgcn_mfma_f32_16x16x32_bf16(chi, bh1, aA1, 0, 0, 0);
            aB0 = __builtin_amdgcn_mfma_f32_16x16x32_bf16(chi, bv0, aB0, 0, 0, 0);
            aB1 = __builtin_amdgcn_mfma_f32_16x16x32_bf16(chi, bv1, aB1, 0, 0, 0);
            aC0 = __builtin_amdgcn_mfma_f32_16x16x32_bf16(clo, bh0, aC0, 0, 0, 0);
            aC1 = __builtin_amdgcn_mfma_f32_16x16x32_bf16(clo, bh1, aC1, 0, 0, 0);
        }
        // phase 2: remaining loads drained
        asm volatile("s_waitcnt vmcnt(0)" ::: "memory");
        __builtin_amdgcn_sched_barrier(0);
#pragma unroll
        for (int kt = 8; kt < NKT; ++kt) {
            short8 bh0 = w0[kt & 3], bv0 = w1[kt & 3];
            short8 bh1 = w2[kt & 3], bv1 = w3[kt & 3];
            if (kt + 4 < NKT) {
                w0[kt & 3] = *(const short8*)(F0 + (kt + 4) * 512);
                w1[kt & 3] = *(const short8*)(F1 + (kt + 4) * 512);
                w2[kt & 3] = *(const short8*)(F2 + (kt + 4) * 512);
                w3[kt & 3] = *(const short8*)(F3 + (kt + 4) * 512);
            }
            short8 chi = __builtin_bit_cast(short8, ah[kt]);
            short8 clo = __builtin_bit_cast(short8, al[kt]);
            aA0 = __builtin_amdgcn_mfma_f32_16x16x32_bf16(chi, bh0, aA0, 0, 0, 0);
            aA1 = __builtin_amdgcn_mfma_f32_16x16x32_bf16(chi, bh1, aA1, 0, 0, 0);
            aB0 = __builtin_amdgcn_mfma_f32_16x16x32_bf16(chi, bv0, aB0, 0, 0, 0);
            aB1 = __builtin_amdgcn_mfma_f32_16x16x32_bf16(chi, bv1, aB1, 0, 0, 0);
            aC0 = __builtin_amdgcn_mfma_f32_16x16x32_bf16(clo, bh0, aC0, 0, 0, 0);
            aC1 = __builtin_amdgcn_mfma_f32_16x16x32_bf16(clo, bh1, aC1, 0, 0, 0);
        }
        floatx4 acc0 = aA0 + aB0 + aC0;
        floatx4 acc1 = aA1 + aB1 + aC1;

        {   // stage gates to LDS  (D frag: row=(lane>>4)*4+r, col=lane&15)
            const int b0r = mt * 16 + (lane >> 4) * 4;
            const int g0 = gp * 2;
#pragma unroll
            for (int r = 0; r < 4; ++r) {
                gbuf[((g0    ) * 32 + b0r + r) * GST + r15] = acc0[r];
                gbuf[((g0 + 1) * 32 + b0r + r) * GST + r15] = acc1[r];
            }
        }
        __syncthreads();

        // Y[t-1] reduction (wave 0): pred long since retired; off hot path
        if (wid == 0 && t > 0) {
            float v = pred;
            v += __shfl_xor(v, 1);  v += __shfl_xor(v, 2);
            v += __shfl_xor(v, 4);  v += __shfl_xor(v, 8);
            v += __shfl_xor(v, 16);
            if (lane == 0)
                store_f32_wt(&Y[(t - 1) * BB + bc * 32 + hs], v + b0);
        }
        {   // elementwise: thread owns (row=ebl2, cols ej, ej+1)
            const float2 gi = *(const float2*)&gbuf[(0 * 32 + ebl2) * GST + ej];
            const float2 gf = *(const float2*)&gbuf[(1 * 32 + ebl2) * GST + ej];
            const float2 gg = *(const float2*)&gbuf[(2 * 32 + ebl2) * GST + ej];
            const float2 go = *(const float2*)&gbuf[(3 * 32 + ebl2) * GST + ej];

            c0 = sigm(gf.x) * c0 + sigm(gi.x) * tanh_(gg.x);
            float ha = sigm(go.x) * tanh_(c0);
            c1 = sigm(gf.y) * c1 + sigm(gi.y) * tanh_(gg.y);
            float hb = sigm(go.y) * tanh_(c1);

            // coalesced h write: one dword per plane into own slice hs
            unsigned short ha_hi, ha_lo, hb_hi, hb_lo;
            split_bits(ha, &ha_hi, &ha_lo);
            split_bits(hb, &hb_hi, &hb_lo);
            unsigned* hw = (unsigned*)hbuf;
            const int woff = hs * 256 + ebl2 * 8 + (tid & 7);
            store_dword_uc(hw + (REGION(nxt, 0) >> 1) + woff,
                           (unsigned)ha_hi | ((unsigned)hb_hi << 16));
            store_dword_uc(hw + (REGION(nxt, 1) >> 1) + woff,
                           (unsigned)ha_lo | ((unsigned)hb_lo << 16));

            // Y partial: uncontended f32 store (replaces 32-way MALL atomics)
            float p = fmaxf(ha, 0.f) * wout2.x + fmaxf(hb, 0.f) * wout2.y;
#pragma unroll
            for (int s = 4; s >= 1; s >>= 1)
                p += __shfl_xor(p, s);
            if ((tid & 7) == 0)
                store_dword_uc(P + ((nxt * 8 + bc) * 32 + hs) * 32 + ebl2,
                               __builtin_bit_cast(unsigned, p));
        }
        // rotating x-stager: owner of time s stages at t=s-1 from regs
        if (t + 1 < TT && hs == ((t + 1) & 31) && stv) {
            unsigned short hi, lo;
            split_bits(xr0, &hi, &lo);
            store_short_uc(hbuf + REGION(nxt, 0) + 32 * 512 + bl0 * 16 + xc0, hi);
            store_short_uc(hbuf + REGION(nxt, 1) + 32 * 512 + bl0 * 16 + xc0, lo);
            split_bits(xr1, &hi, &lo);
            store_short_uc(hbuf + REGION(nxt, 0) + 32 * 512 + bl1 * 16 + xc1, hi);
            store_short_uc(hbuf + REGION(nxt, 1) + 32 * 512 + bl1 * 16 + xc1, lo);
        }
        if (t + 2 < TT && hs == ((t + 2) & 31) && stv) {
            const float2 v = *(const float2*)(X + (t + 2) * XROW + bc * (32 * II) + e0);
            xr0 = v.x; xr1 = v.y;
        }
        if (t + 1 < TT)
            barrier_xcd(bcnt, 32u * (unsigned)(t + 2));
    }

    // ---- epilogue: one more barrier (covers step TT-1 P stores), then
    // reduce Y[TT-1] from parity 0 (TT even). ----
    barrier_xcd(bcnt, 32u * (unsigned)(TT + 1));
    if ((tid >> 6) == 0) {
        const int lane = tid & 63;
        const float* Pc = P + (((TT & 1) * 8 + bc) * 32 + (lane & 31)) * 32 + hs;
        float v = load_f32_uc_issue(Pc);
        asm volatile("s_waitcnt vmcnt(0)" ::: "memory");
        __builtin_amdgcn_sched_barrier(0);
        v += __shfl_xor(v, 1);  v += __shfl_xor(v, 2);
        v += __shfl_xor(v, 4);  v += __shfl_xor(v, 8);
        v += __shfl_xor(v, 16);
        if (lane == 0)
            store_f32_wt(&Y[(TT - 1) * BB + bc * 32 + hs], v + b0);
    }
}

extern "C" void kernel_launch(void* const* d_in, const int* in_sizes, int n_in,
                              void* d_out, int out_size, void* d_ws, size_t ws_size,
                              hipStream_t stream) {
    (void)in_sizes; (void)n_in; (void)out_size; (void)ws_size;
    const float* X    = (const float*)d_in[0];
    const float* Wih  = (const float*)d_in[1];
    const float* Whh  = (const float*)d_in[2];
    const float* bih  = (const float*)d_in[3];
    const float* bhh  = (const float*)d_in[4];
    const float* Wout = (const float*)d_in[5];
    const float* bout = (const float*)d_in[6];
    float* Y = (float*)d_out;

    unsigned* bars = (unsigned*)d_ws;                                  // [0, 2048)
    unsigned short* hbuf = (unsigned short*)((char*)d_ws + 2048);      // 1,114,112 B
    float* P = (float*)((char*)d_ws + 2048 + 32 * PS2 * 2);            // 65,536 B

    hipMemsetAsync(d_ws, 0, 2048, stream);

    const size_t lds = (size_t)(4 * 2 * NKT * 512 * 2) + 128 * GST * 4 + 16;  // 148496
    hipFuncSetAttribute((const void*)lstm_persist,
                        hipFuncAttributeMaxDynamicSharedMemorySize, (int)lds);

    hipLaunchKernelGGL(lstm_persist, dim3(NBLK), dim3(NTH), lds, stream,
                       X, Wih, Whh, bih, bhh, Wout, bout, Y, hbuf, P, bars);
}

// Round 17
// 2060.443 us; speedup vs baseline: 3.4431x; 1.1537x over previous
//
#include <hip/hip_runtime.h>
#include <hip/hip_bf16.h>

#define TT 512
#define BB 256
#define II 13
#define HH 512
#define NBLK 256
#define NTH 256
#define NKT 17              // K tiles of 32 (K = 544 = 34 slices of 16)
#define NSL 34              // slices per plane
#define PS2 (NSL * 512)     // shorts per (buf,plane,bc) region: 17408
#define GST 18              // gbuf row stride (floats)
#define XROW (BB * II)      // 3328

typedef __attribute__((ext_vector_type(8))) short short8;
typedef __attribute__((ext_vector_type(4))) float floatx4;
typedef __attribute__((ext_vector_type(4))) int intx4;

__device__ inline float sigm(float v) { return 1.f / (1.f + __expf(-v)); }
__device__ inline float tanh_(float v) {
    float e = __expf(-2.f * fabsf(v));
    float t = (1.f - e) / (1.f + e);
    return v < 0.f ? -t : t;
}
__device__ inline void split_bits(float v, unsigned short* hi, unsigned short* lo) {
    __hip_bfloat16 h = __float2bfloat16(v);
    float r = v - __bfloat162float(h);
    __hip_bfloat16 l = __float2bfloat16(r);
    *hi = __builtin_bit_cast(unsigned short, h);
    *lo = __builtin_bit_cast(unsigned short, l);
}

// ---- Sync path (MALL, R5/R9/R10-proven): sc1 arrive, sc0sc1 poll. ----
__device__ inline unsigned poll_mall(const unsigned* p) {
    unsigned v;
    asm volatile("global_load_dword %0, %1, off sc0 sc1\n\ts_waitcnt vmcnt(0)"
                 : "=&v"(v) : "v"(p) : "memory");
    return v;
}
__device__ inline void arrive_mall(unsigned* p) {
    asm volatile("global_atomic_add %0, %1, off sc1" :: "v"(p), "v"(1u) : "memory");
}
// ---- Data path (R17): hbuf regions are single-XCD by construction (bc =
// physical XCC_ID of writer AND readers) -> the XCD's L2 is the coherence
// point. R16 used PLAIN stores and raced: plain-store vmcnt retires at the
// L1/coalescer, so the barrier's drain didn't imply L2 visibility for the
// peer CU's sc0 reads (launch 1 passed, replays diverged). R17: sc0 STORES
// (L1-bypass, symmetric with the sc0 loads) — vmcnt retires on L2 ack, so
// drain-before-arrive now means "data at the coherence point".
__device__ inline intx4 load_b128_l2(const void* p) {   // issue only; NO waitcnt
    intx4 v;
    asm volatile("global_load_dwordx4 %0, %1, off sc0" : "=v"(v) : "v"(p));
    return v;
}
__device__ inline void store_short_l2(void* p, unsigned short v) {
    unsigned vv = v;
    asm volatile("global_store_short %0, %1, off sc0" :: "v"(p), "v"(vv) : "memory");
}
__device__ inline void store_dword_l2(void* p, unsigned v) {
    asm volatile("global_store_dword %0, %1, off sc0" :: "v"(p), "v"(v) : "memory");
}
// MALL write-through store: Y init only (Y atomics execute at the MALL).
__device__ inline void store_f32_wt(float* p, float v) {
    asm volatile("global_store_dword %0, %1, off sc0 sc1" :: "v"(p), "v"(v) : "memory");
}

// In-XCD barrier, counter at MALL (R10-proven): __syncthreads drains each
// wave's vmcnt -> all sc0 h-stores are AT the L2 (their coherence point)
// before tid0's arrive. tid0-only poll. Bounded spin.
__device__ inline void barrier_xcd(unsigned* cnt, unsigned target) {
    __syncthreads();
    if (threadIdx.x == 0) {
        arrive_mall(cnt);
        int guard = 0;
        unsigned v;
        do { v = poll_mall(cnt); } while ((int)(v - target) < 0 && ++guard < (1 << 16));
    }
    __syncthreads();
}

__global__ void __launch_bounds__(NTH, 1)
lstm_persist(const float* __restrict__ X,   const float* __restrict__ Wih,
             const float* __restrict__ Whh, const float* __restrict__ bih,
             const float* __restrict__ bhh, const float* __restrict__ Wout,
             const float* __restrict__ bout, float* __restrict__ Y,
             unsigned short* __restrict__ hbuf, unsigned* __restrict__ bars)
{
    extern __shared__ char smem[];
    // W in MFMA-fragment order (R10-validated): frag(gate,plane,kt) = 1KB,
    // lane l owns bytes [16l,16l+16). Conflict-free ds_read_b128.
    unsigned short* Wf = (unsigned short*)smem;          // 4*2*17*512 shorts
    float* gbuf = (float*)(Wf + 4 * 2 * NKT * 512);      // [128][GST] gates
    int* shint = (int*)(gbuf + 128 * GST);

    const int tid = threadIdx.x;

    // ---- runtime role assignment: bc = physical XCD, hs = rank within XCD.
    if (tid == 0) {
        unsigned x = __builtin_amdgcn_s_getreg(20 | (3 << 11)) & 7u; // HW_REG_XCC_ID
        unsigned r = __hip_atomic_fetch_add(bars + 256 + x * 16, 1u,
                        __ATOMIC_RELAXED, __HIP_MEMORY_SCOPE_AGENT);
        shint[0] = (int)x;
        shint[1] = (int)(r & 31u);
    }
    __syncthreads();
    const int bc = shint[0];
    const int hs = shint[1];
    unsigned* bcnt = bars + bc * 32;

    // Block-major hbuf layout (R9/R10): region(buf,plane) per bc; within
    // region [slice 0..33][row 0..31][col 0..15]; logical k = sl*16+col.
    const int regBase = bc * PS2;
#define REGION(buf, plane) (((buf) * 2 + (plane)) * 8 * PS2 + regBase)

    // ---- init: own-slice + (hs==0) shared x/bias slices. sc0 stores
    // (land in this XCD's L2; readers are same-XCD sc0 loads). ----
    {
        unsigned* hw = (unsigned*)hbuf;
        for (int bp = 0; bp < 4; ++bp)
            store_dword_l2(hw + (REGION(bp >> 1, bp & 1) >> 1) + hs * 256 + tid, 0u);
        if (hs == 0) {   // slices 32,33: x0/bias/padding, both bufs+planes
            for (int e = tid; e < 2 * 1024; e += NTH) {
                int buf = e >> 10, off = e & 1023;
                int row = (off >> 4) & 31, col = off & 15;
                unsigned short vh = 0, vl = 0;
                if (off < 512) {           // slice 32
                    if (col == 13) vh = 0x3F80u;                 // bias-one (hi)
                    else if (col < 13 && buf == 0)
                        split_bits(X[(bc * 32 + row) * II + col], &vh, &vl);
                }
                store_short_l2(hbuf + REGION(buf, 0) + 32 * 512 + off, vh);
                store_short_l2(hbuf + REGION(buf, 1) + 32 * 512 + off, vl);
            }
        }
        const float b0 = bout[0];
        for (int i = tid; i < 16 * 32; i += NTH) {   // Y[hs*16..+16)[bc*32..+32)
            int tr = hs * 16 + (i >> 5), cb = bc * 32 + (i & 31);
            store_f32_wt(&Y[tr * BB + cb], b0);
        }
    }
    // ---- W slice -> LDS in fragment order (hi/lo split) ----
    for (int n = 0; n < 64; ++n) {
        int gate = n >> 4, hl = n & 15;
        int gr = gate * HH + hs * 16 + hl;   // global gate row (i,f,g,o order)
        for (int k = tid; k < 544; k += NTH) {
            float v;
            if (k < HH)            v = Whh[gr * HH + k];
            else if (k < HH + II)  v = Wih[gr * II + (k - HH)];
            else if (k == HH + II) v = bih[gr] + bhh[gr];
            else                   v = 0.f;
            unsigned short hi, lo; split_bits(v, &hi, &lo);
            const int slot = (hl + 16 * ((k & 31) >> 3)) * 8 + (k & 7);
            Wf[((gate * 2 + 0) * NKT + (k >> 5)) * 512 + slot] = hi;
            Wf[((gate * 2 + 1) * NKT + (k >> 5)) * 512 + slot] = lo;
        }
    }
    // ---- x_1 register preload (hs==1 stages x_1 at t=0) ----
    const int e0 = 2 * tid;
    const bool stv = (e0 < 32 * II);
    const int bl0 = e0 / II, xc0 = e0 - bl0 * II;
    const int e1 = e0 + 1;
    const int bl1 = e1 / II, xc1 = e1 - bl1 * II;
    float xr0 = 0.f, xr1 = 0.f;
    if (hs == 1 && stv) {
        const float2 v = *(const float2*)(X + XROW + bc * (32 * II) + e0);
        xr0 = v.x; xr1 = v.y;
    }

    barrier_xcd(bcnt, 32u);   // init done (epoch 1)

    // ---- main recurrence (R10 structure; only the hbuf cache path changed) ----
    const int lane = tid & 63, wid = tid >> 6;
    const int mt = wid & 1;                 // batch 16-row half
    const int gp = wid >> 1;                // gate pair {2gp, 2gp+1}
    const int r15  = lane & 15;
    const int kgo  = (lane >> 4) * 8;
    const int slb  = kgo >> 4;              // extra slice within 32-wide tile
    const int lanehoff = (mt * 16 + r15) * 16 + (kgo & 8);
    const int lane8 = lane * 8;
    const unsigned short* F0 = Wf + ((4 * gp + 0) * NKT) * 512 + lane8; // g=2gp  hi
    const unsigned short* F1 = Wf + ((4 * gp + 1) * NKT) * 512 + lane8; // g=2gp  lo
    const unsigned short* F2 = Wf + ((4 * gp + 2) * NKT) * 512 + lane8; // g=2gp+1 hi
    const unsigned short* F3 = Wf + ((4 * gp + 3) * NKT) * 512 + lane8; // g=2gp+1 lo
    float c0 = 0.f, c1 = 0.f;
    const int ebl2 = tid >> 3;              // elementwise row (0..31)
    const int ej   = (tid & 7) * 2;         // elementwise col pair (ej, ej+1)
    const float2 wout2 = *(const float2*)&Wout[hs * 16 + ej];

    for (int t = 0; t < TT; ++t) {
        const int cur = t & 1, nxt = cur ^ 1;
        const unsigned short* Ahi = hbuf + REGION(cur, 0) + lanehoff;
        const unsigned short* Alo = hbuf + REGION(cur, 1) + lanehoff;

        // issue all 34 A-tile loads (L2-direct sc0, coalesced)
        intx4 ah[NKT], al[NKT];
#pragma unroll
        for (int kt = 0; kt < NKT; ++kt) {
            const int so = (kt * 2 + slb) * 512;
            ah[kt] = load_b128_l2(Ahi + so);
            al[kt] = load_b128_l2(Alo + so);
        }
        // W fragment prefetch (kt 0..3, 4-deep rotation) rides the load window
        short8 w0[4], w1[4], w2[4], w3[4];
#pragma unroll
        for (int j = 0; j < 4; ++j) {
            w0[j] = *(const short8*)(F0 + j * 512);
            w1[j] = *(const short8*)(F1 + j * 512);
            w2[j] = *(const short8*)(F2 + j * 512);
            w3[j] = *(const short8*)(F3 + j * 512);
        }
        floatx4 aA0 = {0,0,0,0}, aB0 = {0,0,0,0}, aC0 = {0,0,0,0};
        floatx4 aA1 = {0,0,0,0}, aB1 = {0,0,0,0}, aC1 = {0,0,0,0};

        // phase 1: kt 0..7 ready after 16 oldest loads (34 issued -> vmcnt 18)
        asm volatile("s_waitcnt vmcnt(18)" ::: "memory");
        __builtin_amdgcn_sched_barrier(0);   // rule #18
#pragma unroll
        for (int kt = 0; kt < 8; ++kt) {
            short8 bh0 = w0[kt & 3], bv0 = w1[kt & 3];
            short8 bh1 = w2[kt & 3], bv1 = w3[kt & 3];
            if (kt + 4 < NKT) {
                w0[kt & 3] = *(const short8*)(F0 + (kt + 4) * 512);
                w1[kt & 3] = *(const short8*)(F1 + (kt + 4) * 512);
                w2[kt & 3] = *(const short8*)(F2 + (kt + 4) * 512);
                w3[kt & 3] = *(const short8*)(F3 + (kt + 4) * 512);
            }
            short8 chi = __builtin_bit_cast(short8, ah[kt]);
            short8 clo = __builtin_bit_cast(short8, al[kt]);
            aA0 = __builtin_amdgcn_mfma_f32_16x16x32_bf16(chi, bh0, aA0, 0, 0, 0);
            aA1 = __builtin_amdgcn_mfma_f32_16x16x32_bf16(chi, bh1, aA1, 0, 0, 0);
            aB0 = __builtin_amdgcn_mfma_f32_16x16x32_bf16(chi, bv0, aB0, 0, 0, 0);
            aB1 = __builtin_amdgcn_mfma_f32_16x16x32_bf16(chi, bv1, aB1, 0, 0, 0);
            aC0 = __builtin_amdgcn_mfma_f32_16x16x32_bf16(clo, bh0, aC0, 0, 0, 0);
            aC1 = __builtin_amdgcn_mfma_f32_16x16x32_bf16(clo, bh1, aC1, 0, 0, 0);
        }
        // phase 2: remaining loads drained
        asm volatile("s_waitcnt vmcnt(0)" ::: "memory");
        __builtin_amdgcn_sched_barrier(0);
#pragma unroll
        for (int kt = 8; kt < NKT; ++kt) {
            short8 bh0 = w0[kt & 3], bv0 = w1[kt & 3];
            short8 bh1 = w2[kt & 3], bv1 = w3[kt & 3];
            if (kt + 4 < NKT) {
                w0[kt & 3] = *(const short8*)(F0 + (kt + 4) * 512);
                w1[kt & 3] = *(const short8*)(F1 + (kt + 4) * 512);
                w2[kt & 3] = *(const short8*)(F2 + (kt + 4) * 512);
                w3[kt & 3] = *(const short8*)(F3 + (kt + 4) * 512);
            }
            short8 chi = __builtin_bit_cast(short8, ah[kt]);
            short8 clo = __builtin_bit_cast(short8, al[kt]);
            aA0 = __builtin_amdgcn_mfma_f32_16x16x32_bf16(chi, bh0, aA0, 0, 0, 0);
            aA1 = __builtin_amdgcn_mfma_f32_16x16x32_bf16(chi, bh1, aA1, 0, 0, 0);
            aB0 = __builtin_amdgcn_mfma_f32_16x16x32_bf16(chi, bv0, aB0, 0, 0, 0);
            aB1 = __builtin_amdgcn_mfma_f32_16x16x32_bf16(chi, bv1, aB1, 0, 0, 0);
            aC0 = __builtin_amdgcn_mfma_f32_16x16x32_bf16(clo, bh0, aC0, 0, 0, 0);
            aC1 = __builtin_amdgcn_mfma_f32_16x16x32_bf16(clo, bh1, aC1, 0, 0, 0);
        }
        floatx4 acc0 = aA0 + aB0 + aC0;
        floatx4 acc1 = aA1 + aB1 + aC1;

        {   // stage gates to LDS  (D frag: row=(lane>>4)*4+r, col=lane&15)
            const int b0r = mt * 16 + (lane >> 4) * 4;
            const int g0 = gp * 2;
#pragma unroll
            for (int r = 0; r < 4; ++r) {
                gbuf[((g0    ) * 32 + b0r + r) * GST + r15] = acc0[r];
                gbuf[((g0 + 1) * 32 + b0r + r) * GST + r15] = acc1[r];
            }
        }
        __syncthreads();
        {   // elementwise: thread owns (row=ebl2, cols ej, ej+1)
            const float2 gi = *(const float2*)&gbuf[(0 * 32 + ebl2) * GST + ej];
            const float2 gf = *(const float2*)&gbuf[(1 * 32 + ebl2) * GST + ej];
            const float2 gg = *(const float2*)&gbuf[(2 * 32 + ebl2) * GST + ej];
            const float2 go = *(const float2*)&gbuf[(3 * 32 + ebl2) * GST + ej];

            c0 = sigm(gf.x) * c0 + sigm(gi.x) * tanh_(gg.x);
            float ha = sigm(go.x) * tanh_(c0);
            c1 = sigm(gf.y) * c1 + sigm(gi.y) * tanh_(gg.y);
            float hb = sigm(go.y) * tanh_(c1);

            // coalesced h write: one sc0 dword per plane into own slice hs
            unsigned short ha_hi, ha_lo, hb_hi, hb_lo;
            split_bits(ha, &ha_hi, &ha_lo);
            split_bits(hb, &hb_hi, &hb_lo);
            unsigned* hw = (unsigned*)hbuf;
            const int woff = hs * 256 + ebl2 * 8 + (tid & 7);
            store_dword_l2(hw + (REGION(nxt, 0) >> 1) + woff,
                           (unsigned)ha_hi | ((unsigned)hb_hi << 16));
            store_dword_l2(hw + (REGION(nxt, 1) >> 1) + woff,
                           (unsigned)ha_lo | ((unsigned)hb_lo << 16));

            float p = fmaxf(ha, 0.f) * wout2.x + fmaxf(hb, 0.f) * wout2.y;
#pragma unroll
            for (int s = 4; s >= 1; s >>= 1)
                p += __shfl_xor(p, s);
            if ((tid & 7) == 0)
                atomicAdd(&Y[t * BB + bc * 32 + ebl2], p);
        }
        // rotating x-stager: owner of time s stages at t=s-1 from regs
        if (t + 1 < TT && hs == ((t + 1) & 31) && stv) {
            unsigned short hi, lo;
            split_bits(xr0, &hi, &lo);
            store_short_l2(hbuf + REGION(nxt, 0) + 32 * 512 + bl0 * 16 + xc0, hi);
            store_short_l2(hbuf + REGION(nxt, 1) + 32 * 512 + bl0 * 16 + xc0, lo);
            split_bits(xr1, &hi, &lo);
            store_short_l2(hbuf + REGION(nxt, 0) + 32 * 512 + bl1 * 16 + xc1, hi);
            store_short_l2(hbuf + REGION(nxt, 1) + 32 * 512 + bl1 * 16 + xc1, lo);
        }
        if (t + 2 < TT && hs == ((t + 2) & 31) && stv) {
            const float2 v = *(const float2*)(X + (t + 2) * XROW + bc * (32 * II) + e0);
            xr0 = v.x; xr1 = v.y;
        }
        if (t + 1 < TT)
            barrier_xcd(bcnt, 32u * (unsigned)(t + 2));
    }
}

extern "C" void kernel_launch(void* const* d_in, const int* in_sizes, int n_in,
                              void* d_out, int out_size, void* d_ws, size_t ws_size,
                              hipStream_t stream) {
    (void)in_sizes; (void)n_in; (void)out_size; (void)ws_size;
    const float* X    = (const float*)d_in[0];
    const float* Wih  = (const float*)d_in[1];
    const float* Whh  = (const float*)d_in[2];
    const float* bih  = (const float*)d_in[3];
    const float* bhh  = (const float*)d_in[4];
    const float* Wout = (const float*)d_in[5];
    const float* bout = (const float*)d_in[6];
    float* Y = (float*)d_out;

    unsigned* bars = (unsigned*)d_ws;                                  // [0, 2048)
    unsigned short* hbuf = (unsigned short*)((char*)d_ws + 2048);      // 2x2x8xPS2

    hipMemsetAsync(d_ws, 0, 2048, stream);

    const size_t lds = (size_t)(4 * 2 * NKT * 512 * 2) + 128 * GST * 4 + 16;  // 148496
    hipFuncSetAttribute((const void*)lstm_persist,
                        hipFuncAttributeMaxDynamicSharedMemorySize, (int)lds);

    hipLaunchKernelGGL(lstm_persist, dim3(NBLK), dim3(NTH), lds, stream,
                       X, Wih, Whh, bih, bhh, Wout, bout, Y, hbuf, bars);
}

// Round 19
// 1981.733 us; speedup vs baseline: 3.5799x; 1.0397x over previous
//
#include <hip/hip_runtime.h>
#include <hip/hip_bf16.h>

#define TT 512
#define BB 256
#define II 13
#define HH 512
#define NBLK 256
#define NTH 256
#define NKT 17              // K tiles of 32 (K = 544 = 34 slices of 16)
#define NSL 34              // slices per plane
#define PS2 (NSL * 512)     // shorts per (buf,plane,bc) region: 17408
#define GST 18              // gbuf row stride (floats)
#define XROW (BB * II)      // 3328

typedef __attribute__((ext_vector_type(8))) short short8;
typedef __attribute__((ext_vector_type(4))) float floatx4;
typedef __attribute__((ext_vector_type(4))) int intx4;

__device__ inline float sigm(float v) { return 1.f / (1.f + __expf(-v)); }
__device__ inline float tanh_(float v) {
    float e = __expf(-2.f * fabsf(v));
    float t = (1.f - e) / (1.f + e);
    return v < 0.f ? -t : t;
}
__device__ inline void split_bits(float v, unsigned short* hi, unsigned short* lo) {
    __hip_bfloat16 h = __float2bfloat16(v);
    float r = v - __bfloat162float(h);
    __hip_bfloat16 l = __float2bfloat16(r);
    *hi = __builtin_bit_cast(unsigned short, h);
    *lo = __builtin_bit_cast(unsigned short, l);
}

// ---- Sync path (MALL, R5/R9/R10/R17-proven): sc1 arrive, sc0sc1 poll.
// Coherence ledger (R8/R16/R18): cross-CU POLLING must go through the MALL;
// L2-polled flags stall sporadically. Bulk DATA may ride the XCD L2 (R17).
__device__ inline unsigned poll_mall(const unsigned* p) {
    unsigned v;
    asm volatile("global_load_dword %0, %1, off sc0 sc1\n\ts_waitcnt vmcnt(0)"
                 : "=&v"(v) : "v"(p) : "memory");
    return v;
}
__device__ inline void arrive_mall(unsigned* p) {
    asm volatile("global_atomic_add %0, %1, off sc1" :: "v"(p), "v"(1u) : "memory");
}
// ---- Data path (R17-proven): same-XCD sc0 store -> sc0 load through the
// XCD's L2; sc0-store vmcnt retires on L2 ack, so drain-before-arrive means
// "data at the coherence point".
__device__ inline intx4 load_b128_l2(const void* p) {   // issue only; NO waitcnt
    intx4 v;
    asm volatile("global_load_dwordx4 %0, %1, off sc0" : "=v"(v) : "v"(p));
    return v;
}
__device__ inline void store_short_l2(void* p, unsigned short v) {
    unsigned vv = v;
    asm volatile("global_store_short %0, %1, off sc0" :: "v"(p), "v"(vv) : "memory");
}
__device__ inline void store_dword_l2(void* p, unsigned v) {
    asm volatile("global_store_dword %0, %1, off sc0" :: "v"(p), "v"(v) : "memory");
}
// MALL write-through store: Y init only (Y atomics execute at the MALL).
__device__ inline void store_f32_wt(float* p, float v) {
    asm volatile("global_store_dword %0, %1, off sc0 sc1" :: "v"(p), "v"(v) : "memory");
}

// In-XCD barrier, counter at MALL (R10/R17-proven). __syncthreads drains each
// wave's vmcnt -> all sc0 h-stores are AT the L2 before tid0's arrive.
__device__ inline void barrier_xcd(unsigned* cnt, unsigned target) {
    __syncthreads();
    if (threadIdx.x == 0) {
        arrive_mall(cnt);
        int guard = 0;
        unsigned v;
        do { v = poll_mall(cnt); } while ((int)(v - target) < 0 && ++guard < (1 << 16));
    }
    __syncthreads();
}

__global__ void __launch_bounds__(NTH, 1)
lstm_persist(const float* __restrict__ X,   const float* __restrict__ Wih,
             const float* __restrict__ Whh, const float* __restrict__ bih,
             const float* __restrict__ bhh, const float* __restrict__ Wout,
             const float* __restrict__ bout, float* __restrict__ Y,
             unsigned short* __restrict__ hbuf, unsigned* __restrict__ bars)
{
    extern __shared__ char smem[];
    // W in MFMA-fragment order (R10-validated): frag(gate,plane,kt) = 1KB,
    // lane l owns bytes [16l,16l+16). Conflict-free ds_read_b128.
    unsigned short* Wf = (unsigned short*)smem;          // 4*2*17*512 shorts
    float* gbuf = (float*)(Wf + 4 * 2 * NKT * 512);      // [128][GST] gates
    int* shint = (int*)(gbuf + 128 * GST);

    const int tid = threadIdx.x;

    // ---- runtime role assignment: bc = physical XCD, hs = rank within XCD.
    if (tid == 0) {
        unsigned x = __builtin_amdgcn_s_getreg(20 | (3 << 11)) & 7u; // HW_REG_XCC_ID
        unsigned r = __hip_atomic_fetch_add(bars + 256 + x * 16, 1u,
                        __ATOMIC_RELAXED, __HIP_MEMORY_SCOPE_AGENT);
        shint[0] = (int)x;
        shint[1] = (int)(r & 31u);
    }
    __syncthreads();
    const int bc = shint[0];
    const int hs = shint[1];
    unsigned* bcnt = bars + bc * 32;

    // Block-major hbuf layout (R9/R10): region(buf,plane) per bc; within
    // region [slice 0..33][row 0..31][col 0..15]; logical k = sl*16+col.
    const int regBase = bc * PS2;
#define REGION(buf, plane) (((buf) * 2 + (plane)) * 8 * PS2 + regBase)

    // ---- init: own-slice + (hs==0) shared x/bias slices. sc0 stores
    // (land in this XCD's L2; readers are same-XCD sc0 loads). ----
    {
        unsigned* hw = (unsigned*)hbuf;
        for (int bp = 0; bp < 4; ++bp)
            store_dword_l2(hw + (REGION(bp >> 1, bp & 1) >> 1) + hs * 256 + tid, 0u);
        if (hs == 0) {   // slices 32,33: x0/bias/padding, both bufs+planes
            for (int e = tid; e < 2 * 1024; e += NTH) {
                int buf = e >> 10, off = e & 1023;
                int row = (off >> 4) & 31, col = off & 15;
                unsigned short vh = 0, vl = 0;
                if (off < 512) {           // slice 32
                    if (col == 13) vh = 0x3F80u;                 // bias-one (hi)
                    else if (col < 13 && buf == 0)
                        split_bits(X[(bc * 32 + row) * II + col], &vh, &vl);
                }
                store_short_l2(hbuf + REGION(buf, 0) + 32 * 512 + off, vh);
                store_short_l2(hbuf + REGION(buf, 1) + 32 * 512 + off, vl);
            }
        }
        const float b0 = bout[0];
        for (int i = tid; i < 16 * 32; i += NTH) {   // Y[hs*16..+16)[bc*32..+32)
            int tr = hs * 16 + (i >> 5), cb = bc * 32 + (i & 31);
            store_f32_wt(&Y[tr * BB + cb], b0);
        }
    }
    // ---- W slice -> LDS in fragment order (hi/lo split) ----
    for (int n = 0; n < 64; ++n) {
        int gate = n >> 4, hl = n & 15;
        int gr = gate * HH + hs * 16 + hl;   // global gate row (i,f,g,o order)
        for (int k = tid; k < 544; k += NTH) {
            float v;
            if (k < HH)            v = Whh[gr * HH + k];
            else if (k < HH + II)  v = Wih[gr * II + (k - HH)];
            else if (k == HH + II) v = bih[gr] + bhh[gr];
            else                   v = 0.f;
            unsigned short hi, lo; split_bits(v, &hi, &lo);
            const int slot = (hl + 16 * ((k & 31) >> 3)) * 8 + (k & 7);
            Wf[((gate * 2 + 0) * NKT + (k >> 5)) * 512 + slot] = hi;
            Wf[((gate * 2 + 1) * NKT + (k >> 5)) * 512 + slot] = lo;
        }
    }
    // ---- x_1 register preload (hs==1 stages x_1 at t=0) ----
    const int e0 = 2 * tid;
    const bool stv = (e0 < 32 * II);
    const int bl0 = e0 / II, xc0 = e0 - bl0 * II;
    const int e1 = e0 + 1;
    const int bl1 = e1 / II, xc1 = e1 - bl1 * II;
    float xr0 = 0.f, xr1 = 0.f;
    if (hs == 1 && stv) {
        const float2 v = *(const float2*)(X + XROW + bc * (32 * II) + e0);
        xr0 = v.x; xr1 = v.y;
    }

    barrier_xcd(bcnt, 32u);   // init done (epoch 1)

    // ---- main recurrence (R17 structure; Y atomics deferred one step) ----
    const int lane = tid & 63, wid = tid >> 6;
    const int mt = wid & 1;                 // batch 16-row half
    const int gp = wid >> 1;                // gate pair {2gp, 2gp+1}
    const int r15  = lane & 15;
    const int kgo  = (lane >> 4) * 8;
    const int slb  = kgo >> 4;              // extra slice within 32-wide tile
    const int lanehoff = (mt * 16 + r15) * 16 + (kgo & 8);
    const int lane8 = lane * 8;
    const unsigned short* F0 = Wf + ((4 * gp + 0) * NKT) * 512 + lane8; // g=2gp  hi
    const unsigned short* F1 = Wf + ((4 * gp + 1) * NKT) * 512 + lane8; // g=2gp  lo
    const unsigned short* F2 = Wf + ((4 * gp + 2) * NKT) * 512 + lane8; // g=2gp+1 hi
    const unsigned short* F3 = Wf + ((4 * gp + 3) * NKT) * 512 + lane8; // g=2gp+1 lo
    float c0 = 0.f, c1 = 0.f;
    const int ebl2 = tid >> 3;              // elementwise row (0..31)
    const int ej   = (tid & 7) * 2;         // elementwise col pair (ej, ej+1)
    const float2 wout2 = *(const float2*)&Wout[hs * 16 + ej];

    // deferred Y partial: issued at the TOP of the next iteration so its MALL
    // round trip + 32-way contention ride in the shadow of the compute phase
    // (R17 drained it inside the barrier -> critical path). t=0 dummy adds 0.
    float ypend = 0.f;
    int   ycur  = bc * 32 + ebl2;           // row 0 address; +0.0f is a no-op

    for (int t = 0; t < TT; ++t) {
        const int cur = t & 1, nxt = cur ^ 1;
        const unsigned short* Ahi = hbuf + REGION(cur, 0) + lanehoff;
        const unsigned short* Alo = hbuf + REGION(cur, 1) + lanehoff;

        // issue all 34 A-tile loads (L2-direct sc0, coalesced)
        intx4 ah[NKT], al[NKT];
#pragma unroll
        for (int kt = 0; kt < NKT; ++kt) {
            const int so = (kt * 2 + slb) * 512;
            ah[kt] = load_b128_l2(Ahi + so);
            al[kt] = load_b128_l2(Alo + so);
        }
        // pending Y atomic: pinned AFTER the loads (youngest vmem op) so
        // vmcnt(18)/vmcnt(1) below never wait on its MALL round trip.
        __builtin_amdgcn_sched_barrier(0);
        if ((tid & 7) == 0)
            atomicAdd(&Y[ycur], ypend);
        __builtin_amdgcn_sched_barrier(0);

        // W fragment prefetch (kt 0..3, 4-deep rotation) rides the load window
        short8 w0[4], w1[4], w2[4], w3[4];
#pragma unroll
        for (int j = 0; j < 4; ++j) {
            w0[j] = *(const short8*)(F0 + j * 512);
            w1[j] = *(const short8*)(F1 + j * 512);
            w2[j] = *(const short8*)(F2 + j * 512);
            w3[j] = *(const short8*)(F3 + j * 512);
        }
        floatx4 aA0 = {0,0,0,0}, aB0 = {0,0,0,0}, aC0 = {0,0,0,0};
        floatx4 aA1 = {0,0,0,0}, aB1 = {0,0,0,0}, aC1 = {0,0,0,0};

        // phase 1: kt 0..7 ready after the 17 oldest vmem ops retire
        // (34 loads + 1 atomic outstanding -> vmcnt(18) = 16 loads + 1)
        asm volatile("s_waitcnt vmcnt(18)" ::: "memory");
        __builtin_amdgcn_sched_barrier(0);   // rule #18
#pragma unroll
        for (int kt = 0; kt < 8; ++kt) {
            short8 bh0 = w0[kt & 3], bv0 = w1[kt & 3];
            short8 bh1 = w2[kt & 3], bv1 = w3[kt & 3];
            if (kt + 4 < NKT) {
                w0[kt & 3] = *(const short8*)(F0 + (kt + 4) * 512);
                w1[kt & 3] = *(const short8*)(F1 + (kt + 4) * 512);
                w2[kt & 3] = *(const short8*)(F2 + (kt + 4) * 512);
                w3[kt & 3] = *(const short8*)(F3 + (kt + 4) * 512);
            }
            short8 chi = __builtin_bit_cast(short8, ah[kt]);
            short8 clo = __builtin_bit_cast(short8, al[kt]);
            aA0 = __builtin_amdgcn_mfma_f32_16x16x32_bf16(chi, bh0, aA0, 0, 0, 0);
            aA1 = __builtin_amdgcn_mfma_f32_16x16x32_bf16(chi, bh1, aA1, 0, 0, 0);
            aB0 = __builtin_amdgcn_mfma_f32_16x16x32_bf16(chi, bv0, aB0, 0, 0, 0);
            aB1 = __builtin_amdgcn_mfma_f32_16x16x32_bf16(chi, bv1, aB1, 0, 0, 0);
            aC0 = __builtin_amdgcn_mfma_f32_16x16x32_bf16(clo, bh0, aC0, 0, 0, 0);
            aC1 = __builtin_amdgcn_mfma_f32_16x16x32_bf16(clo, bh1, aC1, 0, 0, 0);
        }
        // phase 2: all loads drained; the Y atomic (youngest) may remain
        asm volatile("s_waitcnt vmcnt(1)" ::: "memory");
        __builtin_amdgcn_sched_barrier(0);
#pragma unroll
        for (int kt = 8; kt < NKT; ++kt) {
            short8 bh0 = w0[kt & 3], bv0 = w1[kt & 3];
            short8 bh1 = w2[kt & 3], bv1 = w3[kt & 3];
            if (kt + 4 < NKT) {
                w0[kt & 3] = *(const short8*)(F0 + (kt + 4) * 512);
                w1[kt & 3] = *(const short8*)(F1 + (kt + 4) * 512);
                w2[kt & 3] = *(const short8*)(F2 + (kt + 4) * 512);
                w3[kt & 3] = *(const short8*)(F3 + (kt + 4) * 512);
            }
            short8 chi = __builtin_bit_cast(short8, ah[kt]);
            short8 clo = __builtin_bit_cast(short8, al[kt]);
            aA0 = __builtin_amdgcn_mfma_f32_16x16x32_bf16(chi, bh0, aA0, 0, 0, 0);
            aA1 = __builtin_amdgcn_mfma_f32_16x16x32_bf16(chi, bh1, aA1, 0, 0, 0);
            aB0 = __builtin_amdgcn_mfma_f32_16x16x32_bf16(chi, bv0, aB0, 0, 0, 0);
            aB1 = __builtin_amdgcn_mfma_f32_16x16x32_bf16(chi, bv1, aB1, 0, 0, 0);
            aC0 = __builtin_amdgcn_mfma_f32_16x16x32_bf16(clo, bh0, aC0, 0, 0, 0);
            aC1 = __builtin_amdgcn_mfma_f32_16x16x32_bf16(clo, bh1, aC1, 0, 0, 0);
        }
        floatx4 acc0 = aA0 + aB0 + aC0;
        floatx4 acc1 = aA1 + aB1 + aC1;

        {   // stage gates to LDS  (D frag: row=(lane>>4)*4+r, col=lane&15)
            const int b0r = mt * 16 + (lane >> 4) * 4;
            const int g0 = gp * 2;
#pragma unroll
            for (int r = 0; r < 4; ++r) {
                gbuf[((g0    ) * 32 + b0r + r) * GST + r15] = acc0[r];
                gbuf[((g0 + 1) * 32 + b0r + r) * GST + r15] = acc1[r];
            }
        }
        __syncthreads();
        {   // elementwise: thread owns (row=ebl2, cols ej, ej+1)
            const float2 gi = *(const float2*)&gbuf[(0 * 32 + ebl2) * GST + ej];
            const float2 gf = *(const float2*)&gbuf[(1 * 32 + ebl2) * GST + ej];
            const float2 gg = *(const float2*)&gbuf[(2 * 32 + ebl2) * GST + ej];
            const float2 go = *(const float2*)&gbuf[(3 * 32 + ebl2) * GST + ej];

            c0 = sigm(gf.x) * c0 + sigm(gi.x) * tanh_(gg.x);
            float ha = sigm(go.x) * tanh_(c0);
            c1 = sigm(gf.y) * c1 + sigm(gi.y) * tanh_(gg.y);
            float hb = sigm(go.y) * tanh_(c1);

            // coalesced h write: one sc0 dword per plane into own slice hs
            unsigned short ha_hi, ha_lo, hb_hi, hb_lo;
            split_bits(ha, &ha_hi, &ha_lo);
            split_bits(hb, &hb_hi, &hb_lo);
            unsigned* hw = (unsigned*)hbuf;
            const int woff = hs * 256 + ebl2 * 8 + (tid & 7);
            store_dword_l2(hw + (REGION(nxt, 0) >> 1) + woff,
                           (unsigned)ha_hi | ((unsigned)hb_hi << 16));
            store_dword_l2(hw + (REGION(nxt, 1) >> 1) + woff,
                           (unsigned)ha_lo | ((unsigned)hb_lo << 16));

            // Y partial: reduce now, DEFER the MALL atomic to next iter top
            float p = fmaxf(ha, 0.f) * wout2.x + fmaxf(hb, 0.f) * wout2.y;
#pragma unroll
            for (int s = 4; s >= 1; s >>= 1)
                p += __shfl_xor(p, s);
            ypend = p;
            ycur  = t * BB + bc * 32 + ebl2;
        }
        // rotating x-stager: owner of time s stages at t=s-1 from regs
        if (t + 1 < TT && hs == ((t + 1) & 31) && stv) {
            unsigned short hi, lo;
            split_bits(xr0, &hi, &lo);
            store_short_l2(hbuf + REGION(nxt, 0) + 32 * 512 + bl0 * 16 + xc0, hi);
            store_short_l2(hbuf + REGION(nxt, 1) + 32 * 512 + bl0 * 16 + xc0, lo);
            split_bits(xr1, &hi, &lo);
            store_short_l2(hbuf + REGION(nxt, 0) + 32 * 512 + bl1 * 16 + xc1, hi);
            store_short_l2(hbuf + REGION(nxt, 1) + 32 * 512 + bl1 * 16 + xc1, lo);
        }
        if (t + 2 < TT && hs == ((t + 2) & 31) && stv) {
            const float2 v = *(const float2*)(X + (t + 2) * XROW + bc * (32 * II) + e0);
            xr0 = v.x; xr1 = v.y;
        }
        if (t + 1 < TT)
            barrier_xcd(bcnt, 32u * (unsigned)(t + 2));
    }
    // final step's Y partial (kernel end guarantees completion)
    if ((tid & 7) == 0)
        atomicAdd(&Y[ycur], ypend);
}

extern "C" void kernel_launch(void* const* d_in, const int* in_sizes, int n_in,
                              void* d_out, int out_size, void* d_ws, size_t ws_size,
                              hipStream_t stream) {
    (void)in_sizes; (void)n_in; (void)out_size; (void)ws_size;
    const float* X    = (const float*)d_in[0];
    const float* Wih  = (const float*)d_in[1];
    const float* Whh  = (const float*)d_in[2];
    const float* bih  = (const float*)d_in[3];
    const float* bhh  = (const float*)d_in[4];
    const float* Wout = (const float*)d_in[5];
    const float* bout = (const float*)d_in[6];
    float* Y = (float*)d_out;

    unsigned* bars = (unsigned*)d_ws;                                  // [0, 2048)
    unsigned short* hbuf = (unsigned short*)((char*)d_ws + 2048);      // 2x2x8xPS2

    hipMemsetAsync(d_ws, 0, 2048, stream);

    const size_t lds = (size_t)(4 * 2 * NKT * 512 * 2) + 128 * GST * 4 + 16;  // 148496
    hipFuncSetAttribute((const void*)lstm_persist,
                        hipFuncAttributeMaxDynamicSharedMemorySize, (int)lds);

    hipLaunchKernelGGL(lstm_persist, dim3(NBLK), dim3(NTH), lds, stream,
                       X, Wih, Whh, bih, bhh, Wout, bout, Y, hbuf, bars);
}